// Round 1
// baseline (672.066 us; speedup 1.0000x reference)
//
#include <hip/hip_runtime.h>

typedef unsigned short u16;
typedef u16 u16x8 __attribute__((ext_vector_type(8)));
typedef __bf16 bf16x8 __attribute__((ext_vector_type(8)));
typedef float f32x4 __attribute__((ext_vector_type(4)));

__device__ __forceinline__ float b2f(u16 h) {
  union { unsigned u; float f; } x; x.u = ((unsigned)h) << 16; return x.f;
}
__device__ __forceinline__ u16 f2b(float f) {
  union { float f; unsigned u; } x; x.f = f;
  unsigned r = x.u + 0x7FFFu + ((x.u >> 16) & 1u);
  return (u16)(r >> 16);
}
__device__ __forceinline__ f32x4 mfma16(bf16x8 a, bf16x8 b, f32x4 c) {
  return __builtin_amdgcn_mfma_f32_16x16x32_bf16(a, b, c, 0, 0, 0);
}

// ---------------- convert f32 -> bf16 ----------------
__global__ __launch_bounds__(256) void f2b_k(const float* __restrict__ in,
                                             u16* __restrict__ out, int n) {
  int i = (blockIdx.x * 256 + threadIdx.x) * 4;
  if (i < n) {
    float4 v = *(const float4*)&in[i];
    out[i + 0] = f2b(v.x); out[i + 1] = f2b(v.y);
    out[i + 2] = f2b(v.z); out[i + 3] = f2b(v.w);
  }
}

// ---------------- GEMM: out[M][N] = A[M][K] @ W[N][K]^T (+epilogue) ----------
// EPI: 0 = bf16 out, 1 = bf16 gelu(out+bias), 2 = bf16 out+bias+resid, 3 = f32 out
// AMODE: 0 plain, 1 A+addvec[k], 2 A*mulmat (elemwise), 3 concat (A1|A2 along K)
template<int EPI, int AMODE>
__global__ __launch_bounds__(256) void gemm_k(
    const u16* __restrict__ A1, const u16* __restrict__ A2, int K1, int K,
    const u16* __restrict__ W, const float* __restrict__ bias,
    const float* __restrict__ addvec, const u16* __restrict__ mulmat,
    const u16* __restrict__ resid, void* __restrict__ outp, int N) {
  __shared__ u16 As[128 * 64];
  __shared__ u16 Ws[128 * 64];
  const int tid = threadIdx.x;
  const int lane = tid & 63;
  const int wv = tid >> 6;
  const int wr = wv >> 1, wc = wv & 1;
  const int lr = lane & 15, lg = lane >> 4;
  const int row0 = blockIdx.x * 128, col0 = blockIdx.y * 128;
  const int sc = (tid & 7) * 8;
  const int sr = tid >> 3;

  f32x4 acc[4][4];
#pragma unroll
  for (int m = 0; m < 4; m++)
#pragma unroll
    for (int n = 0; n < 4; n++) acc[m][n] = f32x4{0.f, 0.f, 0.f, 0.f};

  for (int k0 = 0; k0 < K; k0 += 64) {
#pragma unroll
    for (int ch = 0; ch < 4; ch++) {
      int r = sr + ch * 32;
      int kg = k0 + sc;
      {  // A tile
        int grow = row0 + r;
        const u16* src;
        if (AMODE == 3 && kg >= K1) src = A2 + (size_t)grow * (K - K1) + (kg - K1);
        else                        src = A1 + (size_t)grow * K1 + kg;
        u16x8 v = *(const u16x8*)src;
        if (AMODE == 1) {
#pragma unroll
          for (int j = 0; j < 8; j++) v[j] = f2b(b2f(v[j]) + addvec[kg + j]);
        } else if (AMODE == 2) {
          u16x8 m8 = *(const u16x8*)(mulmat + (size_t)grow * K1 + kg);
#pragma unroll
          for (int j = 0; j < 8; j++) v[j] = f2b(b2f(v[j]) * b2f(m8[j]));
        }
        *(u16x8*)&As[r * 64 + (sc ^ ((r & 7) << 3))] = v;
      }
      {  // W tile
        int wrow = col0 + r;
        u16x8 v = *(const u16x8*)(W + (size_t)wrow * K + kg);
        *(u16x8*)&Ws[r * 64 + (sc ^ ((r & 7) << 3))] = v;
      }
    }
    __syncthreads();
#pragma unroll
    for (int kk = 0; kk < 2; kk++) {
      const int c = kk * 32 + lg * 8;
      bf16x8 af[4], wf[4];
#pragma unroll
      for (int m = 0; m < 4; m++) {
        int r = wr * 64 + m * 16 + lr;
        af[m] = *(const bf16x8*)&As[r * 64 + (c ^ ((r & 7) << 3))];
      }
#pragma unroll
      for (int n = 0; n < 4; n++) {
        int r = wc * 64 + n * 16 + lr;
        wf[n] = *(const bf16x8*)&Ws[r * 64 + (c ^ ((r & 7) << 3))];
      }
#pragma unroll
      for (int m = 0; m < 4; m++)
#pragma unroll
        for (int n = 0; n < 4; n++)
          acc[m][n] = mfma16(af[m], wf[n], acc[m][n]);
    }
    __syncthreads();
  }

#pragma unroll
  for (int m = 0; m < 4; m++)
#pragma unroll
    for (int n = 0; n < 4; n++)
#pragma unroll
      for (int r = 0; r < 4; r++) {
        int grow = row0 + wr * 64 + m * 16 + lg * 4 + r;
        int gcol = col0 + wc * 64 + n * 16 + lr;
        float v = acc[m][n][r];
        if (bias) v += bias[gcol];
        if (EPI == 1) v = 0.5f * v * (1.0f + erff(v * 0.70710678118f));
        if (EPI == 2) v += b2f(resid[(size_t)grow * N + gcol]);
        if (EPI == 3) ((float*)outp)[(size_t)grow * N + gcol] = v;
        else          ((u16*)outp)[(size_t)grow * N + gcol] = f2b(v);
      }
}

// ---------------- V transpose: V[(sb*1024+n)*512 + h*64+d] -> VT[(bh*64+d)*1024+n]
__global__ __launch_bounds__(256) void vtrans_k(const u16* __restrict__ V,
                                                u16* __restrict__ VT) {
  __shared__ u16 t[64][66];
  const int tid = threadIdx.x;
  const int bh = blockIdx.y;  // s*64 + b*8 + h, 0..127
  const int sb = bh >> 3, h = bh & 7;
  const int n0 = blockIdx.x * 64;
#pragma unroll
  for (int i = 0; i < 16; i++) {
    int idx = tid + i * 256;
    int r = idx >> 6, c = idx & 63;
    t[r][c] = V[((size_t)sb * 1024 + n0 + r) * 512 + h * 64 + c];
  }
  __syncthreads();
#pragma unroll
  for (int i = 0; i < 16; i++) {
    int idx = tid + i * 256;
    int r = idx >> 6, c = idx & 63;  // r=d, c=n-local
    VT[((size_t)bh * 64 + r) * 1024 + n0 + c] = t[c][r];
  }
}

// ---------------- fused self-attention (flash-lite, no max-sub) ---------------
__global__ __launch_bounds__(256) void attn_k(const u16* __restrict__ Q,
                                              const u16* __restrict__ Kb,
                                              const u16* __restrict__ VT,
                                              u16* __restrict__ Y) {
  __shared__ u16 Kt[128 * 64];
  __shared__ u16 Vt[64 * 128];
  __shared__ u16 Pt[128 * 128];
  const int tid = threadIdx.x, lane = tid & 63, wv = tid >> 6;
  const int lr = lane & 15, lg = lane >> 4;
  const int by = blockIdx.y;      // s*64 + b*8 + h
  const int sb = by >> 3, h = by & 7;
  const size_t rowbase = (size_t)sb * 1024;
  const int q0 = blockIdx.x * 128;

  bf16x8 qa[2][2];
#pragma unroll
  for (int m = 0; m < 2; m++)
#pragma unroll
    for (int kk = 0; kk < 2; kk++) {
      int r = q0 + wv * 32 + m * 16 + lr;
      int c = h * 64 + kk * 32 + lg * 8;
      qa[m][kk] = *(const bf16x8*)&Q[(rowbase + r) * 512 + c];
    }

  f32x4 o[2][4];
#pragma unroll
  for (int m = 0; m < 2; m++)
#pragma unroll
    for (int n = 0; n < 4; n++) o[m][n] = f32x4{0.f, 0.f, 0.f, 0.f};
  float ls[2][4] = {{0.f, 0.f, 0.f, 0.f}, {0.f, 0.f, 0.f, 0.f}};

  for (int c0 = 0; c0 < 1024; c0 += 128) {
#pragma unroll
    for (int ch = 0; ch < 4; ch++) {  // stage K: 128x64
      int r = (tid >> 3) + ch * 32;
      int c = (tid & 7) * 8;
      u16x8 v = *(const u16x8*)&Kb[(rowbase + c0 + r) * 512 + h * 64 + c];
      *(u16x8*)&Kt[r * 64 + (c ^ ((r & 7) << 3))] = v;
    }
#pragma unroll
    for (int ch = 0; ch < 4; ch++) {  // stage VT chunk: 64 x 128
      int idx = tid * 8 + ch * 2048;
      int r = idx >> 7, c = idx & 127;
      u16x8 v = *(const u16x8*)&VT[((size_t)by * 64 + r) * 1024 + c0 + c];
      *(u16x8*)&Vt[r * 128 + (c ^ ((r & 7) << 3))] = v;
    }
    __syncthreads();

    f32x4 s[2][8];
#pragma unroll
    for (int m = 0; m < 2; m++)
#pragma unroll
      for (int n = 0; n < 8; n++) s[m][n] = f32x4{0.f, 0.f, 0.f, 0.f};
#pragma unroll
    for (int kk = 0; kk < 2; kk++) {
      const int c = kk * 32 + lg * 8;
      bf16x8 kf[8];
#pragma unroll
      for (int n = 0; n < 8; n++) {
        int r = n * 16 + lr;
        kf[n] = *(const bf16x8*)&Kt[r * 64 + (c ^ ((r & 7) << 3))];
      }
#pragma unroll
      for (int m = 0; m < 2; m++)
#pragma unroll
        for (int n = 0; n < 8; n++) s[m][n] = mfma16(qa[m][kk], kf[n], s[m][n]);
    }
    // exp (scores*0.125), accumulate denom, write P to LDS (own-wave rows only)
#pragma unroll
    for (int m = 0; m < 2; m++)
#pragma unroll
      for (int n = 0; n < 8; n++)
#pragma unroll
        for (int r = 0; r < 4; r++) {
          float p = __expf(s[m][n][r] * 0.125f);
          ls[m][r] += p;
          int prow = wv * 32 + m * 16 + lg * 4 + r;
          int pcol = n * 16 + lr;
          Pt[prow * 128 + (pcol ^ ((prow & 7) << 3))] = f2b(p);
        }
    // PV: O += P @ V   (reads only this wave's P rows; in-wave LDS dep is safe)
#pragma unroll
    for (int kc = 0; kc < 4; kc++) {
      const int cc = kc * 32 + lg * 8;
      bf16x8 pa[2], vf[4];
#pragma unroll
      for (int m = 0; m < 2; m++) {
        int r = wv * 32 + m * 16 + lr;
        pa[m] = *(const bf16x8*)&Pt[r * 128 + (cc ^ ((r & 7) << 3))];
      }
#pragma unroll
      for (int n = 0; n < 4; n++) {
        int r = n * 16 + lr;
        vf[n] = *(const bf16x8*)&Vt[r * 128 + (cc ^ ((r & 7) << 3))];
      }
#pragma unroll
      for (int m = 0; m < 2; m++)
#pragma unroll
        for (int n = 0; n < 4; n++) o[m][n] = mfma16(pa[m], vf[n], o[m][n]);
    }
    __syncthreads();
  }

#pragma unroll
  for (int m = 0; m < 2; m++)
#pragma unroll
    for (int r = 0; r < 4; r++) {
      float v = ls[m][r];
      v += __shfl_xor(v, 1); v += __shfl_xor(v, 2);
      v += __shfl_xor(v, 4); v += __shfl_xor(v, 8);
      ls[m][r] = v;
    }
#pragma unroll
  for (int m = 0; m < 2; m++)
#pragma unroll
    for (int n = 0; n < 4; n++)
#pragma unroll
      for (int r = 0; r < 4; r++) {
        int grow = q0 + wv * 32 + m * 16 + lg * 4 + r;
        int gcol = h * 64 + n * 16 + lr;
        Y[(rowbase + grow) * 512 + gcol] = f2b(o[m][n][r] / ls[m][r]);
      }
}

// ---------------- row softmax over 512 (in place, bf16) ----------------------
__global__ __launch_bounds__(256) void rsoftmax_k(u16* __restrict__ X) {
  const int row = blockIdx.x * 4 + (threadIdx.x >> 6);
  const int lane = threadIdx.x & 63;
  u16* p = X + (size_t)row * 512 + lane * 8;
  u16x8 v = *(u16x8*)p;
  float e[8]; float s = 0.f;
#pragma unroll
  for (int j = 0; j < 8; j++) { e[j] = __expf(b2f(v[j])); s += e[j]; }
  for (int x = 1; x < 64; x <<= 1) s += __shfl_xor(s, x);
  float inv = 1.0f / s;
#pragma unroll
  for (int j = 0; j < 8; j++) v[j] = f2b(e[j] * inv);
  *(u16x8*)p = v;
}

// ---------------- 2-key cross attention core ---------------------------------
__global__ __launch_bounds__(256) void twokey_k(
    const u16* __restrict__ qp, const u16* __restrict__ kp0,
    const u16* __restrict__ kp1, const u16* __restrict__ vp0,
    const u16* __restrict__ vp1, u16* __restrict__ o) {
  const int th = blockIdx.x * 256 + threadIdx.x;  // (token, head), 131072 total
  const int t = th >> 3, h = th & 7;
  const size_t base = (size_t)t * 512 + h * 64;
  float s0 = 0.f, s1 = 0.f;
#pragma unroll
  for (int i = 0; i < 8; i++) {
    u16x8 q8 = *(const u16x8*)&qp[base + i * 8];
    u16x8 a8 = *(const u16x8*)&kp0[base + i * 8];
    u16x8 b8 = *(const u16x8*)&kp1[base + i * 8];
#pragma unroll
    for (int j = 0; j < 8; j++) {
      float qf = b2f(q8[j]);
      s0 += qf * b2f(a8[j]); s1 += qf * b2f(b8[j]);
    }
  }
  float e0 = __expf(s0 * 0.125f), e1 = __expf(s1 * 0.125f);
  float rr = 1.0f / (e0 + e1);
  float w0 = e0 * rr, w1 = e1 * rr;
#pragma unroll
  for (int i = 0; i < 8; i++) {
    u16x8 a8 = *(const u16x8*)&vp0[base + i * 8];
    u16x8 b8 = *(const u16x8*)&vp1[base + i * 8];
    u16x8 o8;
#pragma unroll
    for (int j = 0; j < 8; j++) o8[j] = f2b(w0 * b2f(a8[j]) + w1 * b2f(b8[j]));
    *(u16x8*)&o[base + i * 8] = o8;
  }
}

// =============================================================================
extern "C" void kernel_launch(void* const* d_in, const int* in_sizes, int n_in,
                              void* d_out, int out_size, void* d_ws, size_t ws_size,
                              hipStream_t stream) {
  (void)in_sizes; (void)n_in; (void)out_size; (void)ws_size;
  const float* x0  = (const float*)d_in[0];
  const float* x1  = (const float*)d_in[1];
  // d_in[2]=H, d_in[3]=W unused by reference
  const float* Wq  = (const float*)d_in[4];
  const float* Wkv = (const float*)d_in[5];
  const float* Wj1 = (const float*)d_in[6];
  const float* bj1 = (const float*)d_in[7];
  const float* Wj2 = (const float*)d_in[8];
  const float* bj2 = (const float*)d_in[9];
  const float* kn  = (const float*)d_in[10];
  const float* vn  = (const float*)d_in[11];
  const float* Wci[2]  = {(const float*)d_in[12], (const float*)d_in[16]};
  const float* bci[2]  = {(const float*)d_in[13], (const float*)d_in[17]};
  const float* Wco[2]  = {(const float*)d_in[14], (const float*)d_in[18]};
  const float* bco[2]  = {(const float*)d_in[15], (const float*)d_in[19]};
  const float* Wp  = (const float*)d_in[20];
  const float* bp  = (const float*)d_in[21];

  const int T = 8192;            // tokens per stream
  const int TC = T * 512;
  u16* wsb = (u16*)d_ws;
  // bf16 weight area (u16 offsets)
  u16* wqb  = wsb;
  u16* wkvb = wsb + 262144;
  u16* wj1b = wsb + 786432;
  u16* wj2b = wsb + 1310720;
  u16* wcib[2] = {wsb + 1572864, wsb + 2621440};
  u16* wcob[2] = {wsb + 2359296, wsb + 3407872};
  u16* wpb  = wsb + 3670016;
  // 16 MB slots (8388608 u16 each), both streams contiguous per buffer
  const size_t SLOT = 8388608;
  u16* base = wsb + 4194304;
  u16* XB = base;                // x bf16; later reused as REL
  u16* Yb = base + 1 * SLOT;
  u16* P0 = base + 2 * SLOT;
  u16* P1 = base + 3 * SLOT;
  u16* P2 = base + 4 * SLOT;
  u16* P3 = base + 5 * SLOT;
  u16* P4 = base + 6 * SLOT;
  u16* P5 = base + 7 * SLOT;
  u16* REL = XB;

  dim3 blk(256);
  auto cvt = [&](const float* s, u16* d, int n) {
    f2b_k<<<dim3((n / 4 + 255) / 256), blk, 0, stream>>>(s, d, n);
  };
  cvt(x0, XB, TC); cvt(x1, XB + TC, TC);
  cvt(Wq, wqb, 512 * 512);  cvt(Wkv, wkvb, 1024 * 512);
  cvt(Wj1, wj1b, 512 * 1024); cvt(Wj2, wj2b, 512 * 512);
  cvt(Wci[0], wcib[0], 1536 * 512); cvt(Wci[1], wcib[1], 1536 * 512);
  cvt(Wco[0], wcob[0], 512 * 512);  cvt(Wco[1], wcob[1], 512 * 512);
  cvt(Wp, wpb, 512 * 512);

  // self-attn projections (both streams merged, M = 16384)
  gemm_k<0, 0><<<dim3(128, 4), blk, 0, stream>>>(XB, XB, 512, 512, wqb,
      nullptr, nullptr, nullptr, nullptr, P0, 512);                       // q
  gemm_k<0, 0><<<dim3(128, 4), blk, 0, stream>>>(XB, XB, 512, 512, wkvb,
      nullptr, nullptr, nullptr, nullptr, P1, 512);                       // k
  gemm_k<0, 0><<<dim3(128, 4), blk, 0, stream>>>(XB, XB, 512, 512,
      wkvb + 512 * 512, nullptr, nullptr, nullptr, nullptr, P2, 512);     // v
  vtrans_k<<<dim3(16, 128), blk, 0, stream>>>(P2, P5);                    // V^T
  attn_k<<<dim3(8, 128), blk, 0, stream>>>(P0, P1, P5, Yb);               // y

  // judger: rel = softmax(gelu(concat @ Wj1^T + bj1) @ Wj2^T + bj2)
  gemm_k<1, 3><<<dim3(64, 4), blk, 0, stream>>>(Yb, Yb + TC, 512, 1024, wj1b,
      bj1, nullptr, nullptr, nullptr, P3, 512);
  gemm_k<1, 3><<<dim3(64, 4), blk, 0, stream>>>(Yb + TC, Yb, 512, 1024, wj1b,
      bj1, nullptr, nullptr, nullptr, P3 + TC, 512);
  gemm_k<0, 0><<<dim3(128, 4), blk, 0, stream>>>(P3, P3, 512, 512, wj2b,
      bj2, nullptr, nullptr, nullptr, REL, 512);
  rsoftmax_k<<<dim3(4096), blk, 0, stream>>>(REL);

  // cross-attention projections per stream
  for (int s = 0; s < 2; s++) {
    const u16* yq = Yb + (size_t)s * TC;
    const u16* yo = Yb + (size_t)(1 - s) * TC;
    const u16* qw = wcib[s];
    const u16* kw = wcib[s] + 512 * 512;
    const u16* vw = wcib[s] + 1024 * 512;
    const float* bq = bci[s], * bk = bci[s] + 512, * bv = bci[s] + 1024;
    gemm_k<0, 0><<<dim3(64, 4), blk, 0, stream>>>(yq, yq, 512, 512, qw,
        bq, nullptr, nullptr, nullptr, P0 + (size_t)s * TC, 512);         // qp
    gemm_k<0, 1><<<dim3(64, 4), blk, 0, stream>>>(yq, yq, 512, 512, kw,
        bk, kn + s * 512, nullptr, nullptr, P1 + (size_t)s * TC, 512);    // kp0
    gemm_k<0, 2><<<dim3(64, 4), blk, 0, stream>>>(yq, yq, 512, 512, kw,
        bk, nullptr, REL + (size_t)s * TC, nullptr, P2 + (size_t)s * TC, 512); // kp1
    gemm_k<0, 1><<<dim3(64, 4), blk, 0, stream>>>(yq, yq, 512, 512, vw,
        bv, vn + s * 512, nullptr, nullptr, P3 + (size_t)s * TC, 512);    // vp0
    gemm_k<0, 0><<<dim3(64, 4), blk, 0, stream>>>(yo, yo, 512, 512, vw,
        bv, nullptr, nullptr, nullptr, P4 + (size_t)s * TC, 512);         // vp1
  }
  twokey_k<<<dim3(512), blk, 0, stream>>>(P0, P1, P2, P3, P4, P5);        // o

  // new = y + o @ Wout^T + bout ; out = new @ Wp^T + bp (f32)
  for (int s = 0; s < 2; s++) {
    gemm_k<2, 0><<<dim3(64, 4), blk, 0, stream>>>(P5 + (size_t)s * TC,
        P5 + (size_t)s * TC, 512, 512, wcob[s], bco[s], nullptr, nullptr,
        Yb + (size_t)s * TC, P0 + (size_t)s * TC, 512);
  }
  gemm_k<3, 0><<<dim3(128, 4), blk, 0, stream>>>(P0, P0, 512, 512, wpb,
      bp, nullptr, nullptr, nullptr, (float*)d_out, 512);
}

// Round 2
// 436.058 us; speedup vs baseline: 1.5412x; 1.5412x over previous
//
#include <hip/hip_runtime.h>

typedef unsigned short u16;
typedef u16 u16x8 __attribute__((ext_vector_type(8)));
typedef __bf16 bf16x8 __attribute__((ext_vector_type(8)));
typedef float f32x4 __attribute__((ext_vector_type(4)));

__device__ __forceinline__ float b2f(u16 h) {
  union { unsigned u; float f; } x; x.u = ((unsigned)h) << 16; return x.f;
}
__device__ __forceinline__ u16 f2b(float f) {
  union { float f; unsigned u; } x; x.f = f;
  unsigned r = x.u + 0x7FFFu + ((x.u >> 16) & 1u);
  return (u16)(r >> 16);
}
__device__ __forceinline__ f32x4 mfma16(bf16x8 a, bf16x8 b, f32x4 c) {
  return __builtin_amdgcn_mfma_f32_16x16x32_bf16(a, b, c, 0, 0, 0);
}
__device__ __forceinline__ void gload16(const void* g, void* l) {
  __builtin_amdgcn_global_load_lds(
      (const __attribute__((address_space(1))) void*)g,
      (__attribute__((address_space(3))) void*)l, 16, 0, 0);
}

// ---------------- convert f32 -> bf16 ----------------
__global__ __launch_bounds__(256) void f2b_k(const float* __restrict__ in,
                                             u16* __restrict__ out, int n) {
  int i = (blockIdx.x * 256 + threadIdx.x) * 4;
  if (i < n) {
    float4 v = *(const float4*)&in[i];
    out[i + 0] = f2b(v.x); out[i + 1] = f2b(v.y);
    out[i + 2] = f2b(v.z); out[i + 3] = f2b(v.w);
  }
}

// ---------------- GEMM v2: out[M][N] = A[M][K] @ W[N][K]^T (+epilogue) -------
// EPI: 0 bf16 out, 1 bf16 gelu(+bias), 2 bf16 +bias+resid, 3 f32 out
// AMODE: 0 plain (row ^ axor), 1 A+addvec[k], 2 A*mulmat, 3 concat(A, A[row^8192])
// GLA: A staged via global_load_lds (AMODE 0/3 only)
// W/bias/addvec selected per row-block: row0 < 8192 -> *0 else *1
template<int EPI, int AMODE, bool GLA>
__global__ __launch_bounds__(256) void gemm2_k(
    const u16* __restrict__ A, int K1, int K, int axor,
    const u16* __restrict__ W0, const u16* __restrict__ W1,
    const float* __restrict__ b0, const float* __restrict__ b1,
    const float* __restrict__ av0, const float* __restrict__ av1,
    const u16* __restrict__ mulmat,
    const u16* __restrict__ resid, void* __restrict__ outp, int N) {
  __shared__ u16 As[128 * 64];
  __shared__ u16 Ws[128 * 64];
  const int tid = threadIdx.x;
  const int lane = tid & 63;
  const int wv = tid >> 6;
  const int wr = wv >> 1, wc = wv & 1;
  const int lr = lane & 15, lg = lane >> 4;
  const int row0 = blockIdx.x * 128, col0 = blockIdx.y * 128;
  const int strm = (row0 >= 8192) ? 1 : 0;
  const u16* W = strm ? W1 : W0;
  const float* bias = strm ? b1 : b0;
  const float* av = strm ? av1 : av0;
  const int srl = lane >> 3;           // row within 8-row wave group
  const int bcl = (lane & 7) * 16;     // linear byte col in 128B row

  f32x4 acc[4][4];
#pragma unroll
  for (int m = 0; m < 4; m++)
#pragma unroll
    for (int n = 0; n < 4; n++) acc[m][n] = f32x4{0.f, 0.f, 0.f, 0.f};

  for (int k0 = 0; k0 < K; k0 += 64) {
    if constexpr (GLA) {
#pragma unroll
      for (int ch = 0; ch < 4; ch++) {
        int r = ch * 32 + wv * 8 + srl;
        int grow = row0 + r;
        int bcs = bcl ^ ((r & 7) << 4);
        const char* src;
        if constexpr (AMODE == 3) {
          if (k0 < K1) src = (const char*)(A + (size_t)grow * K1) + k0 * 2 + bcs;
          else src = (const char*)(A + (size_t)(grow ^ 8192) * K1) + (k0 - K1) * 2 + bcs;
        } else {
          src = (const char*)(A + (size_t)(grow ^ axor) * K1) + k0 * 2 + bcs;
        }
        gload16(src, &As[(ch * 32 + wv * 8) * 64]);
      }
    } else {
#pragma unroll
      for (int ch = 0; ch < 4; ch++) {
        int r = (tid >> 3) + ch * 32;
        int sc = (tid & 7) * 8;
        int kg = k0 + sc;
        int grow = row0 + r;
        u16x8 v = *(const u16x8*)(A + (size_t)grow * K1 + kg);
        if (AMODE == 1) {
#pragma unroll
          for (int j = 0; j < 8; j++) v[j] = f2b(b2f(v[j]) + av[kg + j]);
        } else if (AMODE == 2) {
          u16x8 m8 = *(const u16x8*)(mulmat + (size_t)grow * K1 + kg);
#pragma unroll
          for (int j = 0; j < 8; j++) v[j] = f2b(b2f(v[j]) * b2f(m8[j]));
        }
        *(u16x8*)&As[r * 64 + (sc ^ ((r & 7) << 3))] = v;
      }
    }
    // W tile via global_load_lds always
#pragma unroll
    for (int ch = 0; ch < 4; ch++) {
      int r = ch * 32 + wv * 8 + srl;
      int bcs = bcl ^ ((r & 7) << 4);
      const char* src = (const char*)(W + (size_t)(col0 + r) * K) + k0 * 2 + bcs;
      gload16(src, &Ws[(ch * 32 + wv * 8) * 64]);
    }
    __syncthreads();
#pragma unroll
    for (int kk = 0; kk < 2; kk++) {
      const int c = kk * 32 + lg * 8;
      bf16x8 af[4], wf[4];
#pragma unroll
      for (int m = 0; m < 4; m++) {
        int r = wr * 64 + m * 16 + lr;
        af[m] = *(const bf16x8*)&As[r * 64 + (c ^ ((r & 7) << 3))];
      }
#pragma unroll
      for (int n = 0; n < 4; n++) {
        int r = wc * 64 + n * 16 + lr;
        wf[n] = *(const bf16x8*)&Ws[r * 64 + (c ^ ((r & 7) << 3))];
      }
#pragma unroll
      for (int m = 0; m < 4; m++)
#pragma unroll
        for (int n = 0; n < 4; n++)
          acc[m][n] = mfma16(af[m], wf[n], acc[m][n]);
    }
    __syncthreads();
  }

#pragma unroll
  for (int m = 0; m < 4; m++)
#pragma unroll
    for (int n = 0; n < 4; n++)
#pragma unroll
      for (int r = 0; r < 4; r++) {
        int grow = row0 + wr * 64 + m * 16 + lg * 4 + r;
        int gcol = col0 + wc * 64 + n * 16 + lr;
        float v = acc[m][n][r];
        if (bias) v += bias[gcol];
        if (EPI == 1) v = 0.5f * v * (1.0f + erff(v * 0.70710678118f));
        if (EPI == 2) v += b2f(resid[(size_t)grow * N + gcol]);
        if (EPI == 3) ((float*)outp)[(size_t)grow * N + gcol] = v;
        else          ((u16*)outp)[(size_t)grow * N + gcol] = f2b(v);
      }
}

// ---------------- V transpose out of merged QKV (stride 1536, col off 1024) --
__global__ __launch_bounds__(256) void vtrans_k(const u16* __restrict__ QKV,
                                                u16* __restrict__ VT) {
  __shared__ u16 t[64][66];
  const int tid = threadIdx.x;
  const int bh = blockIdx.y;  // s*64 + b*8 + h, 0..127
  const int sb = bh >> 3, h = bh & 7;
  const int n0 = blockIdx.x * 64;
#pragma unroll
  for (int i = 0; i < 16; i++) {
    int idx = tid + i * 256;
    int r = idx >> 6, c = idx & 63;
    t[r][c] = QKV[((size_t)sb * 1024 + n0 + r) * 1536 + 1024 + h * 64 + c];
  }
  __syncthreads();
#pragma unroll
  for (int i = 0; i < 16; i++) {
    int idx = tid + i * 256;
    int r = idx >> 6, c = idx & 63;  // r=d, c=n-local
    VT[((size_t)bh * 64 + r) * 1024 + n0 + c] = t[c][r];
  }
}

// ---------------- fused self-attention, 64-col KV tiles, gload_lds staging ---
__global__ __launch_bounds__(256) void attn_k(const u16* __restrict__ QKV,
                                              const u16* __restrict__ VT,
                                              u16* __restrict__ Y) {
  __shared__ u16 Kt[64 * 64];
  __shared__ u16 Vt[64 * 64];
  __shared__ u16 Pt[128 * 64];
  const int STR = 1536;
  const int tid = threadIdx.x, lane = tid & 63, wv = tid >> 6;
  const int lr = lane & 15, lg = lane >> 4;
  const int by = blockIdx.y;      // s*64 + b*8 + h
  const int sb = by >> 3, h = by & 7;
  const size_t rowbase = (size_t)sb * 1024;
  const int q0 = blockIdx.x * 128;
  const int srl = lane >> 3;
  const int bcl = (lane & 7) * 16;

  bf16x8 qa[2][2];
#pragma unroll
  for (int m = 0; m < 2; m++)
#pragma unroll
    for (int kk = 0; kk < 2; kk++) {
      int r = q0 + wv * 32 + m * 16 + lr;
      int c = h * 64 + kk * 32 + lg * 8;
      qa[m][kk] = *(const bf16x8*)&QKV[(rowbase + r) * STR + c];
    }

  f32x4 o[2][4];
#pragma unroll
  for (int m = 0; m < 2; m++)
#pragma unroll
    for (int n = 0; n < 4; n++) o[m][n] = f32x4{0.f, 0.f, 0.f, 0.f};
  float ls[2][4] = {{0.f, 0.f, 0.f, 0.f}, {0.f, 0.f, 0.f, 0.f}};

  for (int c0 = 0; c0 < 1024; c0 += 64) {
#pragma unroll
    for (int ch = 0; ch < 2; ch++) {  // K rows (kcol-local 0..63) x 128B
      int r = ch * 32 + wv * 8 + srl;
      int bcs = bcl ^ ((r & 7) << 4);
      const char* src = (const char*)(QKV + (rowbase + c0 + r) * STR + 512 + h * 64) + bcs;
      gload16(src, &Kt[(ch * 32 + wv * 8) * 64]);
    }
#pragma unroll
    for (int ch = 0; ch < 2; ch++) {  // V^T rows (d 0..63) x 128B
      int r = ch * 32 + wv * 8 + srl;
      int bcs = bcl ^ ((r & 7) << 4);
      const char* src = (const char*)(VT + ((size_t)by * 64 + r) * 1024 + c0) + bcs;
      gload16(src, &Vt[(ch * 32 + wv * 8) * 64]);
    }
    __syncthreads();

    f32x4 s[2][4];
#pragma unroll
    for (int m = 0; m < 2; m++)
#pragma unroll
      for (int n = 0; n < 4; n++) s[m][n] = f32x4{0.f, 0.f, 0.f, 0.f};
#pragma unroll
    for (int kk = 0; kk < 2; kk++) {
      const int c = kk * 32 + lg * 8;
      bf16x8 kf[4];
#pragma unroll
      for (int n = 0; n < 4; n++) {
        int r = n * 16 + lr;
        kf[n] = *(const bf16x8*)&Kt[r * 64 + (c ^ ((r & 7) << 3))];
      }
#pragma unroll
      for (int m = 0; m < 2; m++)
#pragma unroll
        for (int n = 0; n < 4; n++) s[m][n] = mfma16(qa[m][kk], kf[n], s[m][n]);
    }
    // exp(score*0.125), accumulate denom, relay P via LDS (own-wave rows only)
#pragma unroll
    for (int m = 0; m < 2; m++)
#pragma unroll
      for (int n = 0; n < 4; n++)
#pragma unroll
        for (int r = 0; r < 4; r++) {
          float p = __expf(s[m][n][r] * 0.125f);
          ls[m][r] += p;
          int prow = wv * 32 + m * 16 + lg * 4 + r;
          int pcol = n * 16 + lr;
          Pt[prow * 64 + (pcol ^ ((prow & 7) << 3))] = f2b(p);
        }
    // PV: O += P @ V^T^T (reads only this wave's P rows)
#pragma unroll
    for (int kc = 0; kc < 2; kc++) {
      const int cc = kc * 32 + lg * 8;
      bf16x8 pa[2], vf[4];
#pragma unroll
      for (int m = 0; m < 2; m++) {
        int r = wv * 32 + m * 16 + lr;
        pa[m] = *(const bf16x8*)&Pt[r * 64 + (cc ^ ((r & 7) << 3))];
      }
#pragma unroll
      for (int n = 0; n < 4; n++) {
        int r = n * 16 + lr;
        vf[n] = *(const bf16x8*)&Vt[r * 64 + (cc ^ ((r & 7) << 3))];
      }
#pragma unroll
      for (int m = 0; m < 2; m++)
#pragma unroll
        for (int n = 0; n < 4; n++) o[m][n] = mfma16(pa[m], vf[n], o[m][n]);
    }
    __syncthreads();
  }

#pragma unroll
  for (int m = 0; m < 2; m++)
#pragma unroll
    for (int r = 0; r < 4; r++) {
      float v = ls[m][r];
      v += __shfl_xor(v, 1); v += __shfl_xor(v, 2);
      v += __shfl_xor(v, 4); v += __shfl_xor(v, 8);
      ls[m][r] = v;
    }
#pragma unroll
  for (int m = 0; m < 2; m++)
#pragma unroll
    for (int n = 0; n < 4; n++)
#pragma unroll
      for (int r = 0; r < 4; r++) {
        int grow = q0 + wv * 32 + m * 16 + lg * 4 + r;
        int gcol = h * 64 + n * 16 + lr;
        Y[(rowbase + grow) * 512 + gcol] = f2b(o[m][n][r] / ls[m][r]);
      }
}

// ---------------- row softmax over 512 (in place, bf16) ----------------------
__global__ __launch_bounds__(256) void rsoftmax_k(u16* __restrict__ X) {
  const int row = blockIdx.x * 4 + (threadIdx.x >> 6);
  const int lane = threadIdx.x & 63;
  u16* p = X + (size_t)row * 512 + lane * 8;
  u16x8 v = *(u16x8*)p;
  float e[8]; float s = 0.f;
#pragma unroll
  for (int j = 0; j < 8; j++) { e[j] = __expf(b2f(v[j])); s += e[j]; }
  for (int x = 1; x < 64; x <<= 1) s += __shfl_xor(s, x);
  float inv = 1.0f / s;
#pragma unroll
  for (int j = 0; j < 8; j++) v[j] = f2b(e[j] * inv);
  *(u16x8*)p = v;
}

// ---------------- 2-key cross attention core ---------------------------------
__global__ __launch_bounds__(256) void twokey_k(
    const u16* __restrict__ qp, const u16* __restrict__ kp0,
    const u16* __restrict__ kp1, const u16* __restrict__ vp0,
    const u16* __restrict__ vp1, u16* __restrict__ o) {
  const int th = blockIdx.x * 256 + threadIdx.x;  // (token, head)
  const int t = th >> 3, h = th & 7;
  const size_t base = (size_t)t * 512 + h * 64;
  float s0 = 0.f, s1 = 0.f;
#pragma unroll
  for (int i = 0; i < 8; i++) {
    u16x8 q8 = *(const u16x8*)&qp[base + i * 8];
    u16x8 a8 = *(const u16x8*)&kp0[base + i * 8];
    u16x8 b8 = *(const u16x8*)&kp1[base + i * 8];
#pragma unroll
    for (int j = 0; j < 8; j++) {
      float qf = b2f(q8[j]);
      s0 += qf * b2f(a8[j]); s1 += qf * b2f(b8[j]);
    }
  }
  float e0 = __expf(s0 * 0.125f), e1 = __expf(s1 * 0.125f);
  float rr = 1.0f / (e0 + e1);
  float w0 = e0 * rr, w1 = e1 * rr;
#pragma unroll
  for (int i = 0; i < 8; i++) {
    u16x8 a8 = *(const u16x8*)&vp0[base + i * 8];
    u16x8 b8 = *(const u16x8*)&vp1[base + i * 8];
    u16x8 o8;
#pragma unroll
    for (int j = 0; j < 8; j++) o8[j] = f2b(w0 * b2f(a8[j]) + w1 * b2f(b8[j]));
    *(u16x8*)&o[base + i * 8] = o8;
  }
}

// =============================================================================
extern "C" void kernel_launch(void* const* d_in, const int* in_sizes, int n_in,
                              void* d_out, int out_size, void* d_ws, size_t ws_size,
                              hipStream_t stream) {
  (void)in_sizes; (void)n_in; (void)out_size; (void)ws_size;
  const float* x0  = (const float*)d_in[0];
  const float* x1  = (const float*)d_in[1];
  const float* Wq  = (const float*)d_in[4];
  const float* Wkv = (const float*)d_in[5];
  const float* Wj1 = (const float*)d_in[6];
  const float* bj1 = (const float*)d_in[7];
  const float* Wj2 = (const float*)d_in[8];
  const float* bj2 = (const float*)d_in[9];
  const float* kn  = (const float*)d_in[10];
  const float* vn  = (const float*)d_in[11];
  const float* Wci[2]  = {(const float*)d_in[12], (const float*)d_in[16]};
  const float* bci[2]  = {(const float*)d_in[13], (const float*)d_in[17]};
  const float* Wco[2]  = {(const float*)d_in[14], (const float*)d_in[18]};
  const float* bco[2]  = {(const float*)d_in[15], (const float*)d_in[19]};
  const float* Wp  = (const float*)d_in[20];
  const float* bp  = (const float*)d_in[21];

  const int T = 8192;            // tokens per stream
  const int TC = T * 512;
  u16* wsb = (u16*)d_ws;
  // bf16 weight area (u16 offsets); wq and wkv contiguous -> merged 1536x512
  u16* wqb  = wsb;                       // 262144
  u16* wkvb = wsb + 262144;              // 524288
  u16* wj1b = wsb + 786432;              // 524288
  u16* wj2b = wsb + 1310720;             // 262144
  u16* wcib[2] = {wsb + 1572864, wsb + 2621440};   // 786432 each
  u16* wcob[2] = {wsb + 2359296, wsb + 3407872};   // 262144 each
  u16* wpb  = wsb + 3670016;             // 262144
  const size_t SLOT = 8388608;           // 16 MB in u16
  u16* base = wsb + 4194304;
  u16* XB  = base;               // x bf16 [16384][512]; later REL
  u16* Yb  = base + 1 * SLOT;    // self-attn y
  u16* QKV = base + 2 * SLOT;    // [16384][1536], spans slots 2..4; later HID,
                                 // then qp(S3 slot)... see below
  u16* S2 = base + 2 * SLOT;
  u16* S3 = base + 3 * SLOT;
  u16* S4 = base + 4 * SLOT;
  u16* S5 = base + 5 * SLOT;     // VT, later kp1
  u16* S6 = base + 6 * SLOT;
  u16* S7 = base + 7 * SLOT;
  u16* REL = XB;

  dim3 blk(256);
  auto cvt = [&](const float* s, u16* d, int n) {
    f2b_k<<<dim3((n / 4 + 255) / 256), blk, 0, stream>>>(s, d, n);
  };
  cvt(x0, XB, TC); cvt(x1, XB + TC, TC);
  cvt(Wq, wqb, 512 * 512);  cvt(Wkv, wkvb, 1024 * 512);
  cvt(Wj1, wj1b, 512 * 1024); cvt(Wj2, wj2b, 512 * 512);
  cvt(Wci[0], wcib[0], 1536 * 512); cvt(Wci[1], wcib[1], 1536 * 512);
  cvt(Wco[0], wcob[0], 512 * 512);  cvt(Wco[1], wcob[1], 512 * 512);
  cvt(Wp, wpb, 512 * 512);

  // merged qkv projection: [16384][512] @ [1536][512]^T -> QKV [16384][1536]
  gemm2_k<0, 0, true><<<dim3(128, 12), blk, 0, stream>>>(
      XB, 512, 512, 0, wqb, wqb, nullptr, nullptr, nullptr, nullptr,
      nullptr, nullptr, QKV, 1536);
  vtrans_k<<<dim3(16, 128), blk, 0, stream>>>(QKV, S5);
  attn_k<<<dim3(8, 128), blk, 0, stream>>>(QKV, S5, Yb);

  // judger: hid = gelu(concat @ Wj1^T + bj1); rel = softmax(hid @ Wj2^T + bj2)
  gemm2_k<1, 3, true><<<dim3(128, 4), blk, 0, stream>>>(
      Yb, 512, 1024, 0, wj1b, wj1b, bj1, bj1, nullptr, nullptr,
      nullptr, nullptr, S2, 512);
  gemm2_k<0, 0, true><<<dim3(128, 4), blk, 0, stream>>>(
      S2, 512, 512, 0, wj2b, wj2b, bj2, bj2, nullptr, nullptr,
      nullptr, nullptr, REL, 512);
  rsoftmax_k<<<dim3(4096), blk, 0, stream>>>(REL);

  // cross projections, both streams merged (W/bias picked by row block)
  // qp -> S3
  gemm2_k<0, 0, true><<<dim3(128, 4), blk, 0, stream>>>(
      Yb, 512, 512, 0, wcib[0], wcib[1], bci[0], bci[1], nullptr, nullptr,
      nullptr, nullptr, S3, 512);
  // kp0 = (kn_s + y) @ kw + bk -> S4
  gemm2_k<0, 1, false><<<dim3(128, 4), blk, 0, stream>>>(
      Yb, 512, 512, 0, wcib[0] + 262144, wcib[1] + 262144,
      bci[0] + 512, bci[1] + 512, kn, kn + 512, nullptr, nullptr, S4, 512);
  // kp1 = (y * rel) @ kw + bk -> S5 (VT dead)
  gemm2_k<0, 2, false><<<dim3(128, 4), blk, 0, stream>>>(
      Yb, 512, 512, 0, wcib[0] + 262144, wcib[1] + 262144,
      bci[0] + 512, bci[1] + 512, nullptr, nullptr, REL, nullptr, S5, 512);
  // vp0 = (vn_s + y) @ vw + bv -> S2 (HID dead)
  gemm2_k<0, 1, false><<<dim3(128, 4), blk, 0, stream>>>(
      Yb, 512, 512, 0, wcib[0] + 524288, wcib[1] + 524288,
      bci[0] + 1024, bci[1] + 1024, vn, vn + 512, nullptr, nullptr, S2, 512);
  // vp1 = y_other @ vw + bv -> S6  (row ^ 8192 selects the other stream)
  gemm2_k<0, 0, true><<<dim3(128, 4), blk, 0, stream>>>(
      Yb, 512, 512, 8192, wcib[0] + 524288, wcib[1] + 524288,
      bci[0] + 1024, bci[1] + 1024, nullptr, nullptr, nullptr, nullptr, S6, 512);

  twokey_k<<<dim3(512), blk, 0, stream>>>(S3, S4, S5, S2, S6, S7);

  // new = y + o @ Wout^T + bout -> S3 ; out = new @ Wp^T + bp (f32) -> d_out
  gemm2_k<2, 0, true><<<dim3(128, 4), blk, 0, stream>>>(
      S7, 512, 512, 0, wcob[0], wcob[1], bco[0], bco[1], nullptr, nullptr,
      nullptr, Yb, S3, 512);
  gemm2_k<3, 0, true><<<dim3(128, 4), blk, 0, stream>>>(
      S3, 512, 512, 0, wpb, wpb, bp, bp, nullptr, nullptr,
      nullptr, nullptr, d_out, 512);
}

// Round 4
// 429.826 us; speedup vs baseline: 1.5636x; 1.0145x over previous
//
#include <hip/hip_runtime.h>

typedef unsigned short u16;
typedef u16 u16x8 __attribute__((ext_vector_type(8)));
typedef __bf16 bf16x8 __attribute__((ext_vector_type(8)));
typedef __bf16 bf16x2 __attribute__((ext_vector_type(2)));
typedef float f32x4 __attribute__((ext_vector_type(4)));

__device__ __forceinline__ float b2f(u16 h) {
  union { unsigned u; float f; } x; x.u = ((unsigned)h) << 16; return x.f;
}
__device__ __forceinline__ u16 f2b(float f) {
  union { float f; unsigned u; } x; x.f = f;
  unsigned r = x.u + 0x7FFFu + ((x.u >> 16) & 1u);
  return (u16)(r >> 16);
}
__device__ __forceinline__ f32x4 mfma16(bf16x8 a, bf16x8 b, f32x4 c) {
  return __builtin_amdgcn_mfma_f32_16x16x32_bf16(a, b, c, 0, 0, 0);
}
__device__ __forceinline__ void gload16(const void* g, void* l) {
  __builtin_amdgcn_global_load_lds(
      (const __attribute__((address_space(1))) void*)g,
      (__attribute__((address_space(3))) void*)l, 16, 0, 0);
}

// ---------------- conversions ------------------------------------------------
__global__ __launch_bounds__(256) void xcvt_k(const float* __restrict__ x0,
                                              const float* __restrict__ x1,
                                              u16* __restrict__ out) {
  int b = blockIdx.x;
  const float* src = (b < 4096) ? x0 : x1;
  u16* dst = out + (b < 4096 ? 0 : 4194304);
  int i = (b & 4095) * 1024 + threadIdx.x * 4;
  float4 v = *(const float4*)&src[i];
  dst[i + 0] = f2b(v.x); dst[i + 1] = f2b(v.y);
  dst[i + 2] = f2b(v.z); dst[i + 3] = f2b(v.w);
}

__global__ __launch_bounds__(256) void wcvt_k(
    const float* __restrict__ wq, const float* __restrict__ wkv,
    const float* __restrict__ wj1, const float* __restrict__ wj2,
    const float* __restrict__ wci0, const float* __restrict__ wco0,
    const float* __restrict__ wci1, const float* __restrict__ wco1,
    const float* __restrict__ wp, u16* __restrict__ wsb) {
  int b = blockIdx.x; const float* src; size_t doff; int lb;
  if      (b < 256)  { src = wq;   doff = 0;       lb = b; }
  else if (b < 768)  { src = wkv;  doff = 262144;  lb = b - 256; }
  else if (b < 1280) { src = wj1;  doff = 786432;  lb = b - 768; }
  else if (b < 1536) { src = wj2;  doff = 1310720; lb = b - 1280; }
  else if (b < 2304) { src = wci0; doff = 1572864; lb = b - 1536; }
  else if (b < 2560) { src = wco0; doff = 2359296; lb = b - 2304; }
  else if (b < 3328) { src = wci1; doff = 2621440; lb = b - 2560; }
  else if (b < 3584) { src = wco1; doff = 3407872; lb = b - 3328; }
  else               { src = wp;   doff = 3670016; lb = b - 3584; }
  int i = lb * 1024 + threadIdx.x * 4;
  float4 v = *(const float4*)&src[i];
  u16* dst = wsb + doff + i;
  dst[0] = f2b(v.x); dst[1] = f2b(v.y); dst[2] = f2b(v.z); dst[3] = f2b(v.w);
}

// cvec[0..1]=kn_s@kw_s^T, cvec[2..3]=vn_s@vw_s^T  (512 floats each)
__global__ __launch_bounds__(256) void cvec_k(const float* __restrict__ kn,
                                              const float* __restrict__ vn,
                                              const u16* __restrict__ wci0,
                                              const u16* __restrict__ wci1,
                                              float* __restrict__ out) {
  int idx = blockIdx.x * 256 + threadIdx.x;  // 2048
  int which = idx >> 9, col = idx & 511;
  int s = which & 1, isv = which >> 1;
  const float* src = (isv ? vn : kn) + s * 512;
  const u16* w = (s ? wci1 : wci0) + (isv ? 524288 : 262144) + (size_t)col * 512;
  float acc = 0.f;
  for (int k = 0; k < 512; k += 8) {
    u16x8 w8 = *(const u16x8*)&w[k];
#pragma unroll
    for (int j = 0; j < 8; j++) acc += src[k + j] * b2f(w8[j]);
  }
  out[idx] = acc;
}

// ---------------- GEMM v2: out[M][N] = A[M][K] @ W[N][K]^T (+epilogue) -------
// EPI: 0 bf16 out, 1 bf16 gelu(+bias), 2 bf16 +bias+resid, 3 f32 out
// AMODE: 0 plain, 2 A*mulmat, 3 concat(A, A[row^8192]),
//        4 cross-merged: col<1536 normal; col>=1536 -> A[row^8192] @ W[col-512]
// GLA: A staged via global_load_lds (AMODE 0/3/4)
// W/bias selected per OUTPUT-row block: row0 < 8192 -> *0 else *1
template<int EPI, int AMODE, bool GLA>
__global__ __launch_bounds__(256) void gemm2_k(
    const u16* __restrict__ A, int K1, int K,
    const u16* __restrict__ W0, const u16* __restrict__ W1,
    const float* __restrict__ b0, const float* __restrict__ b1,
    const u16* __restrict__ mulmat,
    const u16* __restrict__ resid, void* __restrict__ outp, int N) {
  __shared__ u16 As[128 * 64];
  __shared__ u16 Ws[128 * 64];
  const int tid = threadIdx.x;
  const int lane = tid & 63;
  const int wv = tid >> 6;
  const int wr = wv >> 1, wc = wv & 1;
  const int lr = lane & 15, lg = lane >> 4;
  const int row0 = blockIdx.x * 128, col0 = blockIdx.y * 128;
  const int strm = (row0 >= 8192) ? 1 : 0;
  const u16* W = strm ? W1 : W0;
  const float* bias = strm ? b1 : b0;
  // AMODE 4: 4th column block = vw projection of the OTHER stream's rows
  const int shift = (AMODE == 4 && col0 >= 1536) ? 512 : 0;
  const int cxor  = (AMODE == 4 && col0 >= 1536) ? 8192 : 0;
  const int srl = lane >> 3;           // row within 8-row wave group
  const int bcl = (lane & 7) * 16;     // linear byte col in 128B row

  f32x4 acc[4][4];
#pragma unroll
  for (int m = 0; m < 4; m++)
#pragma unroll
    for (int n = 0; n < 4; n++) acc[m][n] = f32x4{0.f, 0.f, 0.f, 0.f};

  for (int k0 = 0; k0 < K; k0 += 64) {
    if constexpr (GLA) {
#pragma unroll
      for (int ch = 0; ch < 4; ch++) {
        int r = ch * 32 + wv * 8 + srl;
        int grow = row0 + r;
        int bcs = bcl ^ ((r & 7) << 4);
        const char* src;
        if constexpr (AMODE == 3) {
          if (k0 < K1) src = (const char*)(A + (size_t)grow * K1) + k0 * 2 + bcs;
          else src = (const char*)(A + (size_t)(grow ^ 8192) * K1) + (k0 - K1) * 2 + bcs;
        } else {
          src = (const char*)(A + (size_t)(grow ^ cxor) * K1) + k0 * 2 + bcs;
        }
        gload16(src, &As[(ch * 32 + wv * 8) * 64]);
      }
    } else {
#pragma unroll
      for (int ch = 0; ch < 4; ch++) {
        int r = (tid >> 3) + ch * 32;
        int sc = (tid & 7) * 8;
        int kg = k0 + sc;
        int grow = row0 + r;
        u16x8 v = *(const u16x8*)(A + (size_t)grow * K1 + kg);
        if (AMODE == 2) {
          u16x8 m8 = *(const u16x8*)(mulmat + (size_t)grow * K1 + kg);
#pragma unroll
          for (int j = 0; j < 8; j++) v[j] = f2b(b2f(v[j]) * b2f(m8[j]));
        }
        *(u16x8*)&As[r * 64 + (sc ^ ((r & 7) << 3))] = v;
      }
    }
#pragma unroll
    for (int ch = 0; ch < 4; ch++) {
      int r = ch * 32 + wv * 8 + srl;
      int bcs = bcl ^ ((r & 7) << 4);
      const char* src =
          (const char*)(W + (size_t)(col0 - shift + r) * K) + k0 * 2 + bcs;
      gload16(src, &Ws[(ch * 32 + wv * 8) * 64]);
    }
    __syncthreads();
#pragma unroll
    for (int kk = 0; kk < 2; kk++) {
      const int c = kk * 32 + lg * 8;
      bf16x8 af[4], wf[4];
#pragma unroll
      for (int m = 0; m < 4; m++) {
        int r = wr * 64 + m * 16 + lr;
        af[m] = *(const bf16x8*)&As[r * 64 + (c ^ ((r & 7) << 3))];
      }
#pragma unroll
      for (int n = 0; n < 4; n++) {
        int r = wc * 64 + n * 16 + lr;
        wf[n] = *(const bf16x8*)&Ws[r * 64 + (c ^ ((r & 7) << 3))];
      }
#pragma unroll
      for (int m = 0; m < 4; m++)
#pragma unroll
        for (int n = 0; n < 4; n++)
          acc[m][n] = mfma16(af[m], wf[n], acc[m][n]);
    }
    __syncthreads();
  }

#pragma unroll
  for (int m = 0; m < 4; m++)
#pragma unroll
    for (int n = 0; n < 4; n++)
#pragma unroll
      for (int r = 0; r < 4; r++) {
        int grow = row0 + wr * 64 + m * 16 + lg * 4 + r;
        int gcol = col0 + wc * 64 + n * 16 + lr;
        float v = acc[m][n][r];
        if (bias) v += bias[gcol - shift];
        if (EPI == 1) v = 0.5f * v * (1.0f + erff(v * 0.70710678118f));
        if (EPI == 2) v += b2f(resid[(size_t)grow * N + gcol]);
        if (EPI == 3) ((float*)outp)[(size_t)grow * N + gcol] = v;
        else          ((u16*)outp)[(size_t)grow * N + gcol] = f2b(v);
      }
}

// ---------------- V transpose (k-permuted for packed-P PV) -------------------
// VTp[(bh*64+d)*1024 + n0 + p] = V[token n0 + tok(p)][h][d]
// tok(p) = (p>>5)*32 + ((p&31)>>1) + ((p&1)<<4)
__global__ __launch_bounds__(256) void vtrans_k(const u16* __restrict__ QKV,
                                                u16* __restrict__ VT) {
  __shared__ u16 t[64][66];
  const int tid = threadIdx.x;
  const int bh = blockIdx.y;  // s*64 + b*8 + h
  const int sb = bh >> 3, h = bh & 7;
  const int n0 = blockIdx.x * 64;
#pragma unroll
  for (int i = 0; i < 16; i++) {
    int idx = tid + i * 256;
    int r = idx >> 6, c = idx & 63;
    t[r][c] = QKV[((size_t)sb * 1024 + n0 + r) * 1536 + 1024 + h * 64 + c];
  }
  __syncthreads();
#pragma unroll
  for (int i = 0; i < 16; i++) {
    int idx = tid + i * 256;
    int r = idx >> 6, p = idx & 63;  // r=d, p=permuted position
    int tok = ((p >> 5) << 5) + ((p & 31) >> 1) + ((p & 1) << 4);
    VT[((size_t)bh * 64 + r) * 1024 + n0 + p] = t[tok][r];
  }
}

// ---------------- fused self-attention ---------------------------------------
__global__ __launch_bounds__(256) void attn_k(const u16* __restrict__ QKV,
                                              const u16* __restrict__ VT,
                                              u16* __restrict__ Y) {
  __shared__ u16 Kt[64 * 64];
  __shared__ u16 Vt[64 * 64];
  __shared__ u16 Pt[128 * 64];
  const int STR = 1536;
  const int tid = threadIdx.x, lane = tid & 63, wv = tid >> 6;
  const int lr = lane & 15, lg = lane >> 4;
  const int L = blockIdx.x;       // XCD swizzle: same bh -> same L%8 -> same XCD
  const int by = L & 127;         // s*64 + b*8 + h
  const int q0 = (L >> 7) * 128;
  const int sb = by >> 3, h = by & 7;
  const size_t rowbase = (size_t)sb * 1024;
  const int srl = lane >> 3;
  const int bcl = (lane & 7) * 16;
  const float SC = 0.18033688f;   // 0.125 * log2(e); P = exp2(score*SC)

  bf16x8 qa[2][2];                // raw Q fragments (no pre-scale: accuracy)
#pragma unroll
  for (int m = 0; m < 2; m++)
#pragma unroll
    for (int kk = 0; kk < 2; kk++) {
      int r = q0 + wv * 32 + m * 16 + lr;
      int c = h * 64 + kk * 32 + lg * 8;
      qa[m][kk] = *(const bf16x8*)&QKV[(rowbase + r) * STR + c];
    }

  f32x4 o[2][4];
#pragma unroll
  for (int m = 0; m < 2; m++)
#pragma unroll
    for (int n = 0; n < 4; n++) o[m][n] = f32x4{0.f, 0.f, 0.f, 0.f};
  float ls[2][4] = {{0.f, 0.f, 0.f, 0.f}, {0.f, 0.f, 0.f, 0.f}};

  for (int c0 = 0; c0 < 1024; c0 += 64) {
#pragma unroll
    for (int ch = 0; ch < 2; ch++) {  // K tile 64x64
      int r = ch * 32 + wv * 8 + srl;
      int bcs = bcl ^ ((r & 7) << 4);
      const char* src = (const char*)(QKV + (rowbase + c0 + r) * STR + 512 + h * 64) + bcs;
      gload16(src, &Kt[(ch * 32 + wv * 8) * 64]);
    }
#pragma unroll
    for (int ch = 0; ch < 2; ch++) {  // V^T (permuted) tile 64x64
      int r = ch * 32 + wv * 8 + srl;
      int bcs = bcl ^ ((r & 7) << 4);
      const char* src = (const char*)(VT + ((size_t)by * 64 + r) * 1024 + c0) + bcs;
      gload16(src, &Vt[(ch * 32 + wv * 8) * 64]);
    }
    __syncthreads();

    f32x4 s[2][4];
#pragma unroll
    for (int m = 0; m < 2; m++)
#pragma unroll
      for (int n = 0; n < 4; n++) s[m][n] = f32x4{0.f, 0.f, 0.f, 0.f};
#pragma unroll
    for (int kk = 0; kk < 2; kk++) {
      const int c = kk * 32 + lg * 8;
      bf16x8 kf[4];
#pragma unroll
      for (int n = 0; n < 4; n++) {
        int r = n * 16 + lr;
        kf[n] = *(const bf16x8*)&Kt[r * 64 + (c ^ ((r & 7) << 3))];
      }
#pragma unroll
      for (int m = 0; m < 2; m++)
#pragma unroll
        for (int n = 0; n < 4; n++) s[m][n] = mfma16(qa[m][kk], kf[n], s[m][n]);
    }
    // P = exp2(S*SC); pack pairs (col c, col c+16) into u32 at permuted position
#pragma unroll
    for (int m = 0; m < 2; m++)
#pragma unroll
      for (int r = 0; r < 4; r++) {
        int prow = wv * 32 + m * 16 + lg * 4 + r;
        float p00 = __builtin_amdgcn_exp2f(s[m][0][r] * SC);
        float p01 = __builtin_amdgcn_exp2f(s[m][1][r] * SC);
        float p10 = __builtin_amdgcn_exp2f(s[m][2][r] * SC);
        float p11 = __builtin_amdgcn_exp2f(s[m][3][r] * SC);
        ls[m][r] += (p00 + p01) + (p10 + p11);
        bf16x2 w0; w0[0] = (__bf16)p00; w0[1] = (__bf16)p01;
        bf16x2 w1; w1[0] = (__bf16)p10; w1[1] = (__bf16)p11;
        int ib = prow * 64, xr = (prow & 7) << 3;
        *(bf16x2*)&Pt[ib + ((lr * 2) ^ xr)] = w0;
        *(bf16x2*)&Pt[ib + ((32 + lr * 2) ^ xr)] = w1;
      }
    // PV (k-order permuted consistently in Pt and Vt)
#pragma unroll
    for (int kc = 0; kc < 2; kc++) {
      const int cc = kc * 32 + lg * 8;
      bf16x8 pa[2], vf[4];
#pragma unroll
      for (int m = 0; m < 2; m++) {
        int r = wv * 32 + m * 16 + lr;
        pa[m] = *(const bf16x8*)&Pt[r * 64 + (cc ^ ((r & 7) << 3))];
      }
#pragma unroll
      for (int n = 0; n < 4; n++) {
        int r = n * 16 + lr;
        vf[n] = *(const bf16x8*)&Vt[r * 64 + (cc ^ ((r & 7) << 3))];
      }
#pragma unroll
      for (int m = 0; m < 2; m++)
#pragma unroll
        for (int n = 0; n < 4; n++) o[m][n] = mfma16(pa[m], vf[n], o[m][n]);
    }
    __syncthreads();
  }

#pragma unroll
  for (int m = 0; m < 2; m++)
#pragma unroll
    for (int r = 0; r < 4; r++) {
      float v = ls[m][r];
      v += __shfl_xor(v, 1); v += __shfl_xor(v, 2);
      v += __shfl_xor(v, 4); v += __shfl_xor(v, 8);
      ls[m][r] = v;
    }
#pragma unroll
  for (int m = 0; m < 2; m++)
#pragma unroll
    for (int n = 0; n < 4; n++)
#pragma unroll
      for (int r = 0; r < 4; r++) {
        int grow = q0 + wv * 32 + m * 16 + lg * 4 + r;
        int gcol = h * 64 + n * 16 + lr;
        Y[(rowbase + grow) * 512 + gcol] = f2b(o[m][n][r] / ls[m][r]);
      }
}

// ---------------- row softmax over 512 (in place, bf16) ----------------------
__global__ __launch_bounds__(256) void rsoftmax_k(u16* __restrict__ X) {
  const int row = blockIdx.x * 4 + (threadIdx.x >> 6);
  const int lane = threadIdx.x & 63;
  u16* p = X + (size_t)row * 512 + lane * 8;
  u16x8 v = *(u16x8*)p;
  float e[8]; float s = 0.f;
#pragma unroll
  for (int j = 0; j < 8; j++) { e[j] = __expf(b2f(v[j])); s += e[j]; }
  for (int x = 1; x < 64; x <<= 1) s += __shfl_xor(s, x);
  float inv = 1.0f / s;
#pragma unroll
  for (int j = 0; j < 8; j++) v[j] = f2b(e[j] * inv);
  *(u16x8*)p = v;
}

// ---------------- 2-key cross attention, merged-projection inputs ------------
// CP[t] (stride 2048): [0:512]=qp [512:1024]=y@kw+bk [1024:1536]=y@vw+bv
//                      [1536:2048]=y_other@vw_s+bv_s
// kp0 = CP1 + ck; kp1 from KP1; vp0 = CP2 + cv; vp1 = CP3
__global__ __launch_bounds__(256) void twokey2_k(const u16* __restrict__ CP,
                                                 const u16* __restrict__ KP1,
                                                 const float* __restrict__ cvec,
                                                 u16* __restrict__ o) {
  const int th = blockIdx.x * 256 + threadIdx.x;
  const int t = th >> 3, h = th & 7;
  const int s = t >> 13;
  const size_t rb = (size_t)t * 2048 + h * 64;
  const u16* qp = CP + rb;
  const u16* k0 = CP + rb + 512;
  const u16* v0 = CP + rb + 1024;
  const u16* v1 = CP + rb + 1536;
  const u16* k1 = KP1 + (size_t)t * 512 + h * 64;
  const float* ck = cvec + s * 512 + h * 64;
  const float* cv = cvec + 1024 + s * 512 + h * 64;
  float s0 = 0.f, s1 = 0.f;
#pragma unroll
  for (int i = 0; i < 8; i++) {
    u16x8 q8 = *(const u16x8*)&qp[i * 8];
    u16x8 a8 = *(const u16x8*)&k0[i * 8];
    u16x8 b8 = *(const u16x8*)&k1[i * 8];
#pragma unroll
    for (int j = 0; j < 8; j++) {
      float qf = b2f(q8[j]);
      s0 += qf * (b2f(a8[j]) + ck[i * 8 + j]);
      s1 += qf * b2f(b8[j]);
    }
  }
  float e0 = __expf(s0 * 0.125f), e1 = __expf(s1 * 0.125f);
  float rr = 1.0f / (e0 + e1);
  float w0 = e0 * rr, w1 = e1 * rr;
  u16* op = o + (size_t)t * 512 + h * 64;
#pragma unroll
  for (int i = 0; i < 8; i++) {
    u16x8 a8 = *(const u16x8*)&v0[i * 8];
    u16x8 b8 = *(const u16x8*)&v1[i * 8];
    u16x8 o8;
#pragma unroll
    for (int j = 0; j < 8; j++)
      o8[j] = f2b(w0 * (b2f(a8[j]) + cv[i * 8 + j]) + w1 * b2f(b8[j]));
    *(u16x8*)&op[i * 8] = o8;
  }
}

// =============================================================================
extern "C" void kernel_launch(void* const* d_in, const int* in_sizes, int n_in,
                              void* d_out, int out_size, void* d_ws, size_t ws_size,
                              hipStream_t stream) {
  (void)in_sizes; (void)n_in; (void)out_size; (void)ws_size;
  const float* x0  = (const float*)d_in[0];
  const float* x1  = (const float*)d_in[1];
  const float* Wq  = (const float*)d_in[4];
  const float* Wkv = (const float*)d_in[5];
  const float* Wj1 = (const float*)d_in[6];
  const float* bj1 = (const float*)d_in[7];
  const float* Wj2 = (const float*)d_in[8];
  const float* bj2 = (const float*)d_in[9];
  const float* kn  = (const float*)d_in[10];
  const float* vn  = (const float*)d_in[11];
  const float* Wci[2]  = {(const float*)d_in[12], (const float*)d_in[16]};
  const float* bci[2]  = {(const float*)d_in[13], (const float*)d_in[17]};
  const float* Wco[2]  = {(const float*)d_in[14], (const float*)d_in[18]};
  const float* bco[2]  = {(const float*)d_in[15], (const float*)d_in[19]};
  const float* Wp  = (const float*)d_in[20];
  const float* bp  = (const float*)d_in[21];

  u16* wsb = (u16*)d_ws;
  u16* wqb  = wsb;                       // merged with wkv: 1536x512
  u16* wj1b = wsb + 786432;
  u16* wj2b = wsb + 1310720;
  u16* wcib[2] = {wsb + 1572864, wsb + 2621440};
  u16* wcob[2] = {wsb + 2359296, wsb + 3407872};
  u16* wpb  = wsb + 3670016;
  float* cvecb = (float*)(wsb + 3932160);  // 2048 floats
  const size_t SLOT = 8388608;             // 16 MB in u16
  u16* base = wsb + 4194304;
  u16* S0 = base;                // x bf16 -> REL -> new
  u16* S1 = base + 1 * SLOT;     // y (self-attn out)
  u16* S2 = base + 2 * SLOT;     // QKV (S2..S4) -> HID(S2) -> CP (S2..S5)
  u16* S5 = base + 5 * SLOT;     // VTp -> CP tail
  u16* S6 = base + 6 * SLOT;     // KP1
  u16* S7 = base + 7 * SLOT;     // twokey out
  u16* QKV = S2;
  u16* CP  = S2;
  u16* REL = S0;

  dim3 blk(256);
  xcvt_k<<<dim3(8192), blk, 0, stream>>>(x0, x1, S0);
  wcvt_k<<<dim3(3840), blk, 0, stream>>>(Wq, Wkv, Wj1, Wj2, Wci[0], Wco[0],
                                         Wci[1], Wco[1], Wp, wsb);
  cvec_k<<<dim3(8), blk, 0, stream>>>(kn, vn, wcib[0], wcib[1], cvecb);

  // merged qkv projection: [16384][512] @ [1536][512]^T
  gemm2_k<0, 0, true><<<dim3(128, 12), blk, 0, stream>>>(
      S0, 512, 512, wqb, wqb, nullptr, nullptr, nullptr, nullptr, QKV, 1536);
  vtrans_k<<<dim3(16, 128), blk, 0, stream>>>(QKV, S5);
  attn_k<<<dim3(1024), blk, 0, stream>>>(QKV, S5, S1);

  // judger
  gemm2_k<1, 3, true><<<dim3(128, 4), blk, 0, stream>>>(
      S1, 512, 1024, wj1b, wj1b, bj1, bj1, nullptr, nullptr, S2, 512);
  gemm2_k<0, 0, true><<<dim3(128, 4), blk, 0, stream>>>(
      S2, 512, 512, wj2b, wj2b, bj2, bj2, nullptr, nullptr, REL, 512);
  rsoftmax_k<<<dim3(4096), blk, 0, stream>>>(REL);

  // kp1 = (y*rel) @ kw^T + bk -> S6
  gemm2_k<0, 2, false><<<dim3(128, 4), blk, 0, stream>>>(
      S1, 512, 512, wcib[0] + 262144, wcib[1] + 262144,
      bci[0] + 512, bci[1] + 512, REL, nullptr, S6, 512);
  // merged cross projection -> CP [16384][2048]  (4th block: y_other @ vw_s)
  gemm2_k<0, 4, true><<<dim3(128, 16), blk, 0, stream>>>(
      S1, 512, 512, wcib[0], wcib[1], bci[0], bci[1], nullptr, nullptr,
      CP, 2048);

  twokey2_k<<<dim3(512), blk, 0, stream>>>(CP, S6, cvecb, S7);

  // new = y + o @ Wout^T + bout -> S0 ; out = new @ Wp^T + bp (f32)
  gemm2_k<2, 0, true><<<dim3(128, 4), blk, 0, stream>>>(
      S7, 512, 512, wcob[0], wcob[1], bco[0], bco[1], nullptr, S1, S0, 512);
  gemm2_k<3, 0, true><<<dim3(128, 4), blk, 0, stream>>>(
      S0, 512, 512, wpb, wpb, bp, bp, nullptr, nullptr, d_out, 512);
}

// Round 5
// 372.448 us; speedup vs baseline: 1.8045x; 1.1541x over previous
//
#include <hip/hip_runtime.h>

typedef unsigned short u16;
typedef u16 u16x8 __attribute__((ext_vector_type(8)));
typedef __bf16 bf16x8 __attribute__((ext_vector_type(8)));
typedef __bf16 bf16x2 __attribute__((ext_vector_type(2)));
typedef float f32x4 __attribute__((ext_vector_type(4)));

__device__ __forceinline__ float b2f(u16 h) {
  union { unsigned u; float f; } x; x.u = ((unsigned)h) << 16; return x.f;
}
__device__ __forceinline__ u16 f2b(float f) {
  union { float f; unsigned u; } x; x.f = f;
  unsigned r = x.u + 0x7FFFu + ((x.u >> 16) & 1u);
  return (u16)(r >> 16);
}
__device__ __forceinline__ f32x4 mfma16(bf16x8 a, bf16x8 b, f32x4 c) {
  return __builtin_amdgcn_mfma_f32_16x16x32_bf16(a, b, c, 0, 0, 0);
}
__device__ __forceinline__ void gload16(const void* g, void* l) {
  __builtin_amdgcn_global_load_lds(
      (const __attribute__((address_space(1))) void*)g,
      (__attribute__((address_space(3))) void*)l, 16, 0, 0);
}

// ---------------- conversions ------------------------------------------------
__global__ __launch_bounds__(256) void xcvt_k(const float* __restrict__ x0,
                                              const float* __restrict__ x1,
                                              u16* __restrict__ out) {
  int b = blockIdx.x;
  const float* src = (b < 4096) ? x0 : x1;
  u16* dst = out + (b < 4096 ? 0 : 4194304);
  int i = (b & 4095) * 1024 + threadIdx.x * 4;
  float4 v = *(const float4*)&src[i];
  dst[i + 0] = f2b(v.x); dst[i + 1] = f2b(v.y);
  dst[i + 2] = f2b(v.z); dst[i + 3] = f2b(v.w);
}

__global__ __launch_bounds__(256) void wcvt_k(
    const float* __restrict__ wq, const float* __restrict__ wkv,
    const float* __restrict__ wj1, const float* __restrict__ wj2,
    const float* __restrict__ wci0, const float* __restrict__ wco0,
    const float* __restrict__ wci1, const float* __restrict__ wco1,
    const float* __restrict__ wp, u16* __restrict__ wsb) {
  int b = blockIdx.x; const float* src; size_t doff; int lb;
  if      (b < 256)  { src = wq;   doff = 0;       lb = b; }
  else if (b < 768)  { src = wkv;  doff = 262144;  lb = b - 256; }
  else if (b < 1280) { src = wj1;  doff = 786432;  lb = b - 768; }
  else if (b < 1536) { src = wj2;  doff = 1310720; lb = b - 1280; }
  else if (b < 2304) { src = wci0; doff = 1572864; lb = b - 1536; }
  else if (b < 2560) { src = wco0; doff = 2359296; lb = b - 2304; }
  else if (b < 3328) { src = wci1; doff = 2621440; lb = b - 2560; }
  else if (b < 3584) { src = wco1; doff = 3407872; lb = b - 3328; }
  else               { src = wp;   doff = 3670016; lb = b - 3584; }
  int i = lb * 1024 + threadIdx.x * 4;
  float4 v = *(const float4*)&src[i];
  u16* dst = wsb + doff + i;
  dst[0] = f2b(v.x); dst[1] = f2b(v.y); dst[2] = f2b(v.z); dst[3] = f2b(v.w);
}

// cvec[0..1]=kn_s@kw_s^T, cvec[2..3]=vn_s@vw_s^T  (512 floats each)
__global__ __launch_bounds__(256) void cvec_k(const float* __restrict__ kn,
                                              const float* __restrict__ vn,
                                              const u16* __restrict__ wci0,
                                              const u16* __restrict__ wci1,
                                              float* __restrict__ out) {
  int idx = blockIdx.x * 256 + threadIdx.x;  // 2048
  int which = idx >> 9, col = idx & 511;
  int s = which & 1, isv = which >> 1;
  const float* src = (isv ? vn : kn) + s * 512;
  const u16* w = (s ? wci1 : wci0) + (isv ? 524288 : 262144) + (size_t)col * 512;
  float acc = 0.f;
  for (int k = 0; k < 512; k += 8) {
    u16x8 w8 = *(const u16x8*)&w[k];
#pragma unroll
    for (int j = 0; j < 8; j++) acc += src[k + j] * b2f(w8[j]);
  }
  out[idx] = acc;
}

// ---------------- GEMM v3: 512 threads, 128x128 tile, double-buffered --------
// out[M][N] = A[M][K] @ W[N][K]^T (+epilogue)
// EPI: 0 bf16 out, 1 bf16 gelu(+bias), 2 bf16 +bias+resid, 3 f32 out
// AMODE: 0 plain, 2 A*mulmat (reg-staged), 3 concat(A, A[row^8192]),
//        4 cross-merged: col>=1536 -> A[row^8192] @ W[col-512]
// W/bias selected per OUTPUT-row block: row0 < 8192 -> *0 else *1
template<int EPI, int AMODE, bool GLA>
__global__ __launch_bounds__(512, 4) void gemm3_k(
    const u16* __restrict__ A, int K1, int K,
    const u16* __restrict__ W0, const u16* __restrict__ W1,
    const float* __restrict__ b0, const float* __restrict__ b1,
    const u16* __restrict__ mulmat,
    const u16* __restrict__ resid, void* __restrict__ outp, int N) {
  // LDS: A(buf) at buf*16384, W(buf) at buf*16384+8192 (u16 units)
  __shared__ u16 SM[32768];
  const int tid = threadIdx.x;
  const int lane = tid & 63;
  const int wv = tid >> 6;            // 0..7
  const int wr = wv >> 1, wc = wv & 1;
  const int lr = lane & 15, lg = lane >> 4;
  const int row0 = blockIdx.x * 128, col0 = blockIdx.y * 128;
  const int strm = (row0 >= 8192) ? 1 : 0;
  const u16* W = strm ? W1 : W0;
  const float* bias = strm ? b1 : b0;
  const int shift = (AMODE == 4 && col0 >= 1536) ? 512 : 0;
  const int cxor  = (AMODE == 4 && col0 >= 1536) ? 8192 : 0;
  const int rL = tid >> 3;            // 0..63
  const int bcl = (lane & 7) * 16;    // linear byte col in 128B row

  f32x4 acc[2][4];
#pragma unroll
  for (int m = 0; m < 2; m++)
#pragma unroll
    for (int n = 0; n < 4; n++) acc[m][n] = f32x4{0.f, 0.f, 0.f, 0.f};

  const int nk = K >> 6;

  auto stage = [&](int k0, int buf) {
    const int Ab = buf * 16384, Wb = buf * 16384 + 8192;
#pragma unroll
    for (int ch = 0; ch < 2; ch++) {
      int r = ch * 64 + rL;
      int bcs = bcl ^ ((r & 7) << 4);
      if constexpr (GLA) {
        const char* asrc;
        if constexpr (AMODE == 3) {
          if (k0 < K1)
            asrc = (const char*)(A + (size_t)(row0 + r) * K1) + k0 * 2 + bcs;
          else
            asrc = (const char*)(A + (size_t)((row0 + r) ^ 8192) * K1) +
                   (k0 - K1) * 2 + bcs;
        } else {
          asrc = (const char*)(A + (size_t)((row0 + r) ^ cxor) * K1) +
                 k0 * 2 + bcs;
        }
        gload16(asrc, &SM[Ab + (ch * 64 + wv * 8) * 64]);
      } else {
        int sc = (lane & 7) * 8;
        int kg = k0 + sc;
        u16x8 v = *(const u16x8*)(A + (size_t)(row0 + r) * K1 + kg);
        if (AMODE == 2) {
          u16x8 m8 = *(const u16x8*)(mulmat + (size_t)(row0 + r) * K1 + kg);
#pragma unroll
          for (int j = 0; j < 8; j++) v[j] = f2b(b2f(v[j]) * b2f(m8[j]));
        }
        *(u16x8*)&SM[Ab + r * 64 + (sc ^ ((r & 7) << 3))] = v;
      }
      const char* wsrc =
          (const char*)(W + (size_t)(col0 - shift + r) * K) + k0 * 2 + bcs;
      gload16(wsrc, &SM[Wb + (ch * 64 + wv * 8) * 64]);
    }
  };

  stage(0, 0);
  __syncthreads();
  for (int t = 0; t < nk; t++) {
    const int buf = t & 1;
    if (t + 1 < nk) stage((t + 1) * 64, buf ^ 1);   // overlap next-tile loads
    const int Ab = buf * 16384, Wb = buf * 16384 + 8192;
#pragma unroll
    for (int kk = 0; kk < 2; kk++) {
      const int c = kk * 32 + lg * 8;
      bf16x8 af[2], wf[4];
#pragma unroll
      for (int m = 0; m < 2; m++) {
        int r = wr * 32 + m * 16 + lr;
        af[m] = *(const bf16x8*)&SM[Ab + r * 64 + (c ^ ((r & 7) << 3))];
      }
#pragma unroll
      for (int n = 0; n < 4; n++) {
        int r = wc * 64 + n * 16 + lr;
        wf[n] = *(const bf16x8*)&SM[Wb + r * 64 + (c ^ ((r & 7) << 3))];
      }
#pragma unroll
      for (int m = 0; m < 2; m++)
#pragma unroll
        for (int n = 0; n < 4; n++)
          acc[m][n] = mfma16(af[m], wf[n], acc[m][n]);
    }
    __syncthreads();
  }

#pragma unroll
  for (int m = 0; m < 2; m++)
#pragma unroll
    for (int n = 0; n < 4; n++)
#pragma unroll
      for (int r = 0; r < 4; r++) {
        int grow = row0 + wr * 32 + m * 16 + lg * 4 + r;
        int gcol = col0 + wc * 64 + n * 16 + lr;
        float v = acc[m][n][r];
        if (bias) v += bias[gcol - shift];
        if (EPI == 1) v = 0.5f * v * (1.0f + erff(v * 0.70710678118f));
        if (EPI == 2) v += b2f(resid[(size_t)grow * N + gcol]);
        if (EPI == 3) ((float*)outp)[(size_t)grow * N + gcol] = v;
        else          ((u16*)outp)[(size_t)grow * N + gcol] = f2b(v);
      }
}

// ---------------- V transpose (k-permuted for packed-P PV) -------------------
// VTp[(bh*64+d)*1024 + n0 + p] = V[token n0 + tok(p)][h][d]
// tok(p) = (p>>5)*32 + ((p&31)>>1) + ((p&1)<<4)
__global__ __launch_bounds__(256) void vtrans_k(const u16* __restrict__ QKV,
                                                u16* __restrict__ VT) {
  __shared__ u16 t[64][66];
  const int tid = threadIdx.x;
  const int bh = blockIdx.y;  // s*64 + b*8 + h
  const int sb = bh >> 3, h = bh & 7;
  const int n0 = blockIdx.x * 64;
#pragma unroll
  for (int i = 0; i < 16; i++) {
    int idx = tid + i * 256;
    int r = idx >> 6, c = idx & 63;
    t[r][c] = QKV[((size_t)sb * 1024 + n0 + r) * 1536 + 1024 + h * 64 + c];
  }
  __syncthreads();
#pragma unroll
  for (int i = 0; i < 16; i++) {
    int idx = tid + i * 256;
    int r = idx >> 6, p = idx & 63;  // r=d, p=permuted position
    int tok = ((p >> 5) << 5) + ((p & 31) >> 1) + ((p & 1) << 4);
    VT[((size_t)bh * 64 + r) * 1024 + n0 + p] = t[tok][r];
  }
}

// ---------------- fused self-attention (double-buffered K/V) -----------------
__global__ __launch_bounds__(256) void attn_k(const u16* __restrict__ QKV,
                                              const u16* __restrict__ VT,
                                              u16* __restrict__ Y) {
  // LDS: K(buf) at buf*8192, V(buf) at buf*8192+4096, Pt at 16384 (u16 units)
  __shared__ u16 SM[24576];
  const int STR = 1536;
  const int tid = threadIdx.x, lane = tid & 63, wv = tid >> 6;
  const int lr = lane & 15, lg = lane >> 4;
  const int L = blockIdx.x;       // XCD swizzle: same bh -> same L%8 -> same XCD
  const int by = L & 127;         // s*64 + b*8 + h
  const int q0 = (L >> 7) * 128;
  const int sb = by >> 3, h = by & 7;
  const size_t rowbase = (size_t)sb * 1024;
  const int bcl = (lane & 7) * 16;
  const float SC = 0.18033688f;   // 0.125 * log2(e); P = exp2(score*SC)

  bf16x8 qa[2][2];                // raw Q fragments
#pragma unroll
  for (int m = 0; m < 2; m++)
#pragma unroll
    for (int kk = 0; kk < 2; kk++) {
      int r = q0 + wv * 32 + m * 16 + lr;
      int c = h * 64 + kk * 32 + lg * 8;
      qa[m][kk] = *(const bf16x8*)&QKV[(rowbase + r) * STR + c];
    }

  f32x4 o[2][4];
#pragma unroll
  for (int m = 0; m < 2; m++)
#pragma unroll
    for (int n = 0; n < 4; n++) o[m][n] = f32x4{0.f, 0.f, 0.f, 0.f};
  float ls[2][4] = {{0.f, 0.f, 0.f, 0.f}, {0.f, 0.f, 0.f, 0.f}};

  auto stagekv = [&](int c0, int buf) {
#pragma unroll
    for (int ch = 0; ch < 2; ch++) {
      int r = ch * 32 + (tid >> 3);   // 0..63
      int bcs = bcl ^ ((r & 7) << 4);
      const char* ks =
          (const char*)(QKV + (rowbase + c0 + r) * STR + 512 + h * 64) + bcs;
      gload16(ks, &SM[buf * 8192 + (ch * 32 + wv * 8) * 64]);
      const char* vs =
          (const char*)(VT + ((size_t)by * 64 + r) * 1024 + c0) + bcs;
      gload16(vs, &SM[buf * 8192 + 4096 + (ch * 32 + wv * 8) * 64]);
    }
  };

  stagekv(0, 0);
  __syncthreads();
  for (int t = 0; t < 16; t++) {
    const int buf = t & 1;
    if (t < 15) stagekv((t + 1) * 64, buf ^ 1);   // overlap next-tile loads
    const int Kb = buf * 8192, Vb = buf * 8192 + 4096;

    f32x4 s[2][4];
#pragma unroll
    for (int m = 0; m < 2; m++)
#pragma unroll
      for (int n = 0; n < 4; n++) s[m][n] = f32x4{0.f, 0.f, 0.f, 0.f};
#pragma unroll
    for (int kk = 0; kk < 2; kk++) {
      const int c = kk * 32 + lg * 8;
      bf16x8 kf[4];
#pragma unroll
      for (int n = 0; n < 4; n++) {
        int r = n * 16 + lr;
        kf[n] = *(const bf16x8*)&SM[Kb + r * 64 + (c ^ ((r & 7) << 3))];
      }
#pragma unroll
      for (int m = 0; m < 2; m++)
#pragma unroll
        for (int n = 0; n < 4; n++) s[m][n] = mfma16(qa[m][kk], kf[n], s[m][n]);
    }
    // P = exp2(S*SC); pack col pairs (c, c+16) as u32 at permuted position
#pragma unroll
    for (int m = 0; m < 2; m++)
#pragma unroll
      for (int r = 0; r < 4; r++) {
        int prow = wv * 32 + m * 16 + lg * 4 + r;
        float p00 = __builtin_amdgcn_exp2f(s[m][0][r] * SC);
        float p01 = __builtin_amdgcn_exp2f(s[m][1][r] * SC);
        float p10 = __builtin_amdgcn_exp2f(s[m][2][r] * SC);
        float p11 = __builtin_amdgcn_exp2f(s[m][3][r] * SC);
        ls[m][r] += (p00 + p01) + (p10 + p11);
        bf16x2 w0; w0[0] = (__bf16)p00; w0[1] = (__bf16)p01;
        bf16x2 w1; w1[0] = (__bf16)p10; w1[1] = (__bf16)p11;
        int ib = 16384 + prow * 64, xr = (prow & 7) << 3;
        *(bf16x2*)&SM[ib + ((lr * 2) ^ xr)] = w0;
        *(bf16x2*)&SM[ib + ((32 + lr * 2) ^ xr)] = w1;
      }
    // PV (k-order permuted consistently in Pt and Vt); Pt is wave-private
#pragma unroll
    for (int kc = 0; kc < 2; kc++) {
      const int cc = kc * 32 + lg * 8;
      bf16x8 pa[2], vf[4];
#pragma unroll
      for (int m = 0; m < 2; m++) {
        int r = wv * 32 + m * 16 + lr;
        pa[m] = *(const bf16x8*)&SM[16384 + r * 64 + (cc ^ ((r & 7) << 3))];
      }
#pragma unroll
      for (int n = 0; n < 4; n++) {
        int r = n * 16 + lr;
        vf[n] = *(const bf16x8*)&SM[Vb + r * 64 + (cc ^ ((r & 7) << 3))];
      }
#pragma unroll
      for (int m = 0; m < 2; m++)
#pragma unroll
        for (int n = 0; n < 4; n++) o[m][n] = mfma16(pa[m], vf[n], o[m][n]);
    }
    __syncthreads();
  }

#pragma unroll
  for (int m = 0; m < 2; m++)
#pragma unroll
    for (int r = 0; r < 4; r++) {
      float v = ls[m][r];
      v += __shfl_xor(v, 1); v += __shfl_xor(v, 2);
      v += __shfl_xor(v, 4); v += __shfl_xor(v, 8);
      ls[m][r] = v;
    }
#pragma unroll
  for (int m = 0; m < 2; m++)
#pragma unroll
    for (int n = 0; n < 4; n++)
#pragma unroll
      for (int r = 0; r < 4; r++) {
        int grow = q0 + wv * 32 + m * 16 + lg * 4 + r;
        int gcol = h * 64 + n * 16 + lr;
        Y[(rowbase + grow) * 512 + gcol] = f2b(o[m][n][r] / ls[m][r]);
      }
}

// ---------------- row softmax over 512 (in place, bf16) ----------------------
__global__ __launch_bounds__(256) void rsoftmax_k(u16* __restrict__ X) {
  const int row = blockIdx.x * 4 + (threadIdx.x >> 6);
  const int lane = threadIdx.x & 63;
  u16* p = X + (size_t)row * 512 + lane * 8;
  u16x8 v = *(u16x8*)p;
  float e[8]; float s = 0.f;
#pragma unroll
  for (int j = 0; j < 8; j++) { e[j] = __expf(b2f(v[j])); s += e[j]; }
  for (int x = 1; x < 64; x <<= 1) s += __shfl_xor(s, x);
  float inv = 1.0f / s;
#pragma unroll
  for (int j = 0; j < 8; j++) v[j] = f2b(e[j] * inv);
  *(u16x8*)p = v;
}

// ---------------- 2-key cross attention, merged-projection inputs ------------
// CP[t] (stride 2048): [0:512]=qp [512:1024]=y@kw+bk [1024:1536]=y@vw+bv
//                      [1536:2048]=y_other@vw_s+bv_s
__global__ __launch_bounds__(256) void twokey2_k(const u16* __restrict__ CP,
                                                 const u16* __restrict__ KP1,
                                                 const float* __restrict__ cvec,
                                                 u16* __restrict__ o) {
  const int th = blockIdx.x * 256 + threadIdx.x;
  const int t = th >> 3, h = th & 7;
  const int s = t >> 13;
  const size_t rb = (size_t)t * 2048 + h * 64;
  const u16* qp = CP + rb;
  const u16* k0 = CP + rb + 512;
  const u16* v0 = CP + rb + 1024;
  const u16* v1 = CP + rb + 1536;
  const u16* k1 = KP1 + (size_t)t * 512 + h * 64;
  const float* ck = cvec + s * 512 + h * 64;
  const float* cv = cvec + 1024 + s * 512 + h * 64;
  float s0 = 0.f, s1 = 0.f;
#pragma unroll
  for (int i = 0; i < 8; i++) {
    u16x8 q8 = *(const u16x8*)&qp[i * 8];
    u16x8 a8 = *(const u16x8*)&k0[i * 8];
    u16x8 b8 = *(const u16x8*)&k1[i * 8];
#pragma unroll
    for (int j = 0; j < 8; j++) {
      float qf = b2f(q8[j]);
      s0 += qf * (b2f(a8[j]) + ck[i * 8 + j]);
      s1 += qf * b2f(b8[j]);
    }
  }
  float e0 = __expf(s0 * 0.125f), e1 = __expf(s1 * 0.125f);
  float rr = 1.0f / (e0 + e1);
  float w0 = e0 * rr, w1 = e1 * rr;
  u16* op = o + (size_t)t * 512 + h * 64;
#pragma unroll
  for (int i = 0; i < 8; i++) {
    u16x8 a8 = *(const u16x8*)&v0[i * 8];
    u16x8 b8 = *(const u16x8*)&v1[i * 8];
    u16x8 o8;
#pragma unroll
    for (int j = 0; j < 8; j++)
      o8[j] = f2b(w0 * (b2f(a8[j]) + cv[i * 8 + j]) + w1 * b2f(b8[j]));
    *(u16x8*)&op[i * 8] = o8;
  }
}

// =============================================================================
extern "C" void kernel_launch(void* const* d_in, const int* in_sizes, int n_in,
                              void* d_out, int out_size, void* d_ws, size_t ws_size,
                              hipStream_t stream) {
  (void)in_sizes; (void)n_in; (void)out_size; (void)ws_size;
  const float* x0  = (const float*)d_in[0];
  const float* x1  = (const float*)d_in[1];
  const float* Wq  = (const float*)d_in[4];
  const float* Wkv = (const float*)d_in[5];
  const float* Wj1 = (const float*)d_in[6];
  const float* bj1 = (const float*)d_in[7];
  const float* Wj2 = (const float*)d_in[8];
  const float* bj2 = (const float*)d_in[9];
  const float* kn  = (const float*)d_in[10];
  const float* vn  = (const float*)d_in[11];
  const float* Wci[2]  = {(const float*)d_in[12], (const float*)d_in[16]};
  const float* bci[2]  = {(const float*)d_in[13], (const float*)d_in[17]};
  const float* Wco[2]  = {(const float*)d_in[14], (const float*)d_in[18]};
  const float* bco[2]  = {(const float*)d_in[15], (const float*)d_in[19]};
  const float* Wp  = (const float*)d_in[20];
  const float* bp  = (const float*)d_in[21];

  u16* wsb = (u16*)d_ws;
  u16* wqb  = wsb;                       // merged with wkv: 1536x512
  u16* wj1b = wsb + 786432;
  u16* wj2b = wsb + 1310720;
  u16* wcib[2] = {wsb + 1572864, wsb + 2621440};
  u16* wcob[2] = {wsb + 2359296, wsb + 3407872};
  u16* wpb  = wsb + 3670016;
  float* cvecb = (float*)(wsb + 3932160);  // 2048 floats
  const size_t SLOT = 8388608;             // 16 MB in u16
  u16* base = wsb + 4194304;
  u16* S0 = base;                // x bf16 -> REL -> new
  u16* S1 = base + 1 * SLOT;     // y (self-attn out)
  u16* S2 = base + 2 * SLOT;     // QKV (S2..S4) -> HID(S2) -> CP (S2..S5)
  u16* S5 = base + 5 * SLOT;     // VTp -> CP tail
  u16* S6 = base + 6 * SLOT;     // KP1
  u16* S7 = base + 7 * SLOT;     // twokey out
  u16* QKV = S2;
  u16* CP  = S2;
  u16* REL = S0;

  dim3 blk(256), gblk(512);
  xcvt_k<<<dim3(8192), blk, 0, stream>>>(x0, x1, S0);
  wcvt_k<<<dim3(3840), blk, 0, stream>>>(Wq, Wkv, Wj1, Wj2, Wci[0], Wco[0],
                                         Wci[1], Wco[1], Wp, wsb);
  cvec_k<<<dim3(8), blk, 0, stream>>>(kn, vn, wcib[0], wcib[1], cvecb);

  // merged qkv projection: [16384][512] @ [1536][512]^T
  gemm3_k<0, 0, true><<<dim3(128, 12), gblk, 0, stream>>>(
      S0, 512, 512, wqb, wqb, nullptr, nullptr, nullptr, nullptr, QKV, 1536);
  vtrans_k<<<dim3(16, 128), blk, 0, stream>>>(QKV, S5);
  attn_k<<<dim3(1024), blk, 0, stream>>>(QKV, S5, S1);

  // judger
  gemm3_k<1, 3, true><<<dim3(128, 4), gblk, 0, stream>>>(
      S1, 512, 1024, wj1b, wj1b, bj1, bj1, nullptr, nullptr, S2, 512);
  gemm3_k<0, 0, true><<<dim3(128, 4), gblk, 0, stream>>>(
      S2, 512, 512, wj2b, wj2b, bj2, bj2, nullptr, nullptr, REL, 512);
  rsoftmax_k<<<dim3(4096), blk, 0, stream>>>(REL);

  // kp1 = (y*rel) @ kw^T + bk -> S6
  gemm3_k<0, 2, false><<<dim3(128, 4), gblk, 0, stream>>>(
      S1, 512, 512, wcib[0] + 262144, wcib[1] + 262144,
      bci[0] + 512, bci[1] + 512, REL, nullptr, S6, 512);
  // merged cross projection -> CP [16384][2048]  (4th block: y_other @ vw_s)
  gemm3_k<0, 4, true><<<dim3(128, 16), gblk, 0, stream>>>(
      S1, 512, 512, wcib[0], wcib[1], bci[0], bci[1], nullptr, nullptr,
      CP, 2048);

  twokey2_k<<<dim3(512), blk, 0, stream>>>(CP, S6, cvecb, S7);

  // new = y + o @ Wout^T + bout -> S0 ; out = new @ Wp^T + bp (f32)
  gemm3_k<2, 0, true><<<dim3(128, 4), gblk, 0, stream>>>(
      S7, 512, 512, wcob[0], wcob[1], bco[0], bco[1], nullptr, S1, S0, 512);
  gemm3_k<3, 0, true><<<dim3(128, 4), gblk, 0, stream>>>(
      S0, 512, 512, wpb, wpb, bp, bp, nullptr, nullptr, d_out, 512);
}

// Round 6
// 321.760 us; speedup vs baseline: 2.0887x; 1.1575x over previous
//
#include <hip/hip_runtime.h>

typedef unsigned short u16;
typedef u16 u16x8 __attribute__((ext_vector_type(8)));
typedef __bf16 bf16x8 __attribute__((ext_vector_type(8)));
typedef __bf16 bf16x2 __attribute__((ext_vector_type(2)));
typedef float f32x4 __attribute__((ext_vector_type(4)));

__device__ __forceinline__ float b2f(u16 h) {
  union { unsigned u; float f; } x; x.u = ((unsigned)h) << 16; return x.f;
}
__device__ __forceinline__ u16 f2b(float f) {
  union { float f; unsigned u; } x; x.f = f;
  unsigned r = x.u + 0x7FFFu + ((x.u >> 16) & 1u);
  return (u16)(r >> 16);
}
__device__ __forceinline__ f32x4 mfma16(bf16x8 a, bf16x8 b, f32x4 c) {
  return __builtin_amdgcn_mfma_f32_16x16x32_bf16(a, b, c, 0, 0, 0);
}
__device__ __forceinline__ void gload16(const void* g, void* l) {
  __builtin_amdgcn_global_load_lds(
      (const __attribute__((address_space(1))) void*)g,
      (__attribute__((address_space(3))) void*)l, 16, 0, 0);
}

// ---------------- conversions ------------------------------------------------
__global__ __launch_bounds__(256) void xcvt_k(const float* __restrict__ x0,
                                              const float* __restrict__ x1,
                                              u16* __restrict__ out) {
  int b = blockIdx.x;
  const float* src = (b < 4096) ? x0 : x1;
  u16* dst = out + (b < 4096 ? 0 : 4194304);
  int i = (b & 4095) * 1024 + threadIdx.x * 4;
  float4 v = *(const float4*)&src[i];
  dst[i + 0] = f2b(v.x); dst[i + 1] = f2b(v.y);
  dst[i + 2] = f2b(v.z); dst[i + 3] = f2b(v.w);
}

__global__ __launch_bounds__(256) void wcvt_k(
    const float* __restrict__ wq, const float* __restrict__ wkv,
    const float* __restrict__ wj1, const float* __restrict__ wj2,
    const float* __restrict__ wci0, const float* __restrict__ wco0,
    const float* __restrict__ wci1, const float* __restrict__ wco1,
    const float* __restrict__ wp, u16* __restrict__ wsb) {
  int b = blockIdx.x; const float* src; size_t doff; int lb;
  if      (b < 256)  { src = wq;   doff = 0;       lb = b; }
  else if (b < 768)  { src = wkv;  doff = 262144;  lb = b - 256; }
  else if (b < 1280) { src = wj1;  doff = 786432;  lb = b - 768; }
  else if (b < 1536) { src = wj2;  doff = 1310720; lb = b - 1280; }
  else if (b < 2304) { src = wci0; doff = 1572864; lb = b - 1536; }
  else if (b < 2560) { src = wco0; doff = 2359296; lb = b - 2304; }
  else if (b < 3328) { src = wci1; doff = 2621440; lb = b - 2560; }
  else if (b < 3584) { src = wco1; doff = 3407872; lb = b - 3328; }
  else               { src = wp;   doff = 3670016; lb = b - 3584; }
  int i = lb * 1024 + threadIdx.x * 4;
  float4 v = *(const float4*)&src[i];
  u16* dst = wsb + doff + i;
  dst[0] = f2b(v.x); dst[1] = f2b(v.y); dst[2] = f2b(v.z); dst[3] = f2b(v.w);
}

// cvec[0..1]=kn_s@kw_s^T, cvec[2..3]=vn_s@vw_s^T  (512 floats each)
__global__ __launch_bounds__(256) void cvec_k(const float* __restrict__ kn,
                                              const float* __restrict__ vn,
                                              const u16* __restrict__ wci0,
                                              const u16* __restrict__ wci1,
                                              float* __restrict__ out) {
  int idx = blockIdx.x * 256 + threadIdx.x;  // 2048
  int which = idx >> 9, col = idx & 511;
  int s = which & 1, isv = which >> 1;
  const float* src = (isv ? vn : kn) + s * 512;
  const u16* w = (s ? wci1 : wci0) + (isv ? 524288 : 262144) + (size_t)col * 512;
  float acc = 0.f;
  for (int k = 0; k < 512; k += 8) {
    u16x8 w8 = *(const u16x8*)&w[k];
#pragma unroll
    for (int j = 0; j < 8; j++) acc += src[k + j] * b2f(w8[j]);
  }
  out[idx] = acc;
}

// ---------------- GEMM v3: 512 threads, 128x128 tile, double-buffered --------
// out[M][N] = A[M][K] @ W[N][K]^T (+epilogue)
// EPI: 0 bf16 out, 1 bf16 gelu(+bias), 2 bf16 +bias+resid, 3 f32 out
// AMODE: 0 plain, 2 A*mulmat (reg-staged), 3 concat(A, A[row^8192]),
//        4 cross-merged: col>=1536 -> A[row^8192] @ W[col-512]
// W/bias selected per OUTPUT-row block: row0 < 8192 -> *0 else *1
template<int EPI, int AMODE, bool GLA>
__global__ __launch_bounds__(512, 4) void gemm3_k(
    const u16* __restrict__ A, int K1, int K,
    const u16* __restrict__ W0, const u16* __restrict__ W1,
    const float* __restrict__ b0, const float* __restrict__ b1,
    const u16* __restrict__ mulmat,
    const u16* __restrict__ resid, void* __restrict__ outp, int N) {
  // LDS: A(buf) at buf*16384, W(buf) at buf*16384+8192 (u16 units)
  __shared__ u16 SM[32768];
  const int tid = threadIdx.x;
  const int lane = tid & 63;
  const int wv = tid >> 6;            // 0..7
  const int wr = wv >> 1, wc = wv & 1;
  const int lr = lane & 15, lg = lane >> 4;
  const int row0 = blockIdx.x * 128, col0 = blockIdx.y * 128;
  const int strm = (row0 >= 8192) ? 1 : 0;
  const u16* W = strm ? W1 : W0;
  const float* bias = strm ? b1 : b0;
  const int shift = (AMODE == 4 && col0 >= 1536) ? 512 : 0;
  const int cxor  = (AMODE == 4 && col0 >= 1536) ? 8192 : 0;
  const int rL = tid >> 3;            // 0..63
  const int bcl = (lane & 7) * 16;    // linear byte col in 128B row

  f32x4 acc[2][4];
#pragma unroll
  for (int m = 0; m < 2; m++)
#pragma unroll
    for (int n = 0; n < 4; n++) acc[m][n] = f32x4{0.f, 0.f, 0.f, 0.f};

  const int nk = K >> 6;

  auto stage = [&](int k0, int buf) {
    const int Ab = buf * 16384, Wb = buf * 16384 + 8192;
#pragma unroll
    for (int ch = 0; ch < 2; ch++) {
      int r = ch * 64 + rL;
      int bcs = bcl ^ ((r & 7) << 4);
      if constexpr (GLA) {
        const char* asrc;
        if constexpr (AMODE == 3) {
          if (k0 < K1)
            asrc = (const char*)(A + (size_t)(row0 + r) * K1) + k0 * 2 + bcs;
          else
            asrc = (const char*)(A + (size_t)((row0 + r) ^ 8192) * K1) +
                   (k0 - K1) * 2 + bcs;
        } else {
          asrc = (const char*)(A + (size_t)((row0 + r) ^ cxor) * K1) +
                 k0 * 2 + bcs;
        }
        gload16(asrc, &SM[Ab + (ch * 64 + wv * 8) * 64]);
      } else {
        int sc = (lane & 7) * 8;
        int kg = k0 + sc;
        u16x8 v = *(const u16x8*)(A + (size_t)(row0 + r) * K1 + kg);
        if (AMODE == 2) {
          u16x8 m8 = *(const u16x8*)(mulmat + (size_t)(row0 + r) * K1 + kg);
#pragma unroll
          for (int j = 0; j < 8; j++) v[j] = f2b(b2f(v[j]) * b2f(m8[j]));
        }
        *(u16x8*)&SM[Ab + r * 64 + (sc ^ ((r & 7) << 3))] = v;
      }
      const char* wsrc =
          (const char*)(W + (size_t)(col0 - shift + r) * K) + k0 * 2 + bcs;
      gload16(wsrc, &SM[Wb + (ch * 64 + wv * 8) * 64]);
    }
  };

  stage(0, 0);
  __syncthreads();
  for (int t = 0; t < nk; t++) {
    const int buf = t & 1;
    if (t + 1 < nk) stage((t + 1) * 64, buf ^ 1);   // overlap next-tile loads
    const int Ab = buf * 16384, Wb = buf * 16384 + 8192;
#pragma unroll
    for (int kk = 0; kk < 2; kk++) {
      const int c = kk * 32 + lg * 8;
      bf16x8 af[2], wf[4];
#pragma unroll
      for (int m = 0; m < 2; m++) {
        int r = wr * 32 + m * 16 + lr;
        af[m] = *(const bf16x8*)&SM[Ab + r * 64 + (c ^ ((r & 7) << 3))];
      }
#pragma unroll
      for (int n = 0; n < 4; n++) {
        int r = wc * 64 + n * 16 + lr;
        wf[n] = *(const bf16x8*)&SM[Wb + r * 64 + (c ^ ((r & 7) << 3))];
      }
#pragma unroll
      for (int m = 0; m < 2; m++)
#pragma unroll
        for (int n = 0; n < 4; n++)
          acc[m][n] = mfma16(af[m], wf[n], acc[m][n]);
    }
    __syncthreads();
  }

#pragma unroll
  for (int m = 0; m < 2; m++)
#pragma unroll
    for (int n = 0; n < 4; n++)
#pragma unroll
      for (int r = 0; r < 4; r++) {
        int grow = row0 + wr * 32 + m * 16 + lg * 4 + r;
        int gcol = col0 + wc * 64 + n * 16 + lr;
        float v = acc[m][n][r];
        if (bias) v += bias[gcol - shift];
        if (EPI == 1) v = 0.5f * v * (1.0f + erff(v * 0.70710678118f));
        if (EPI == 2) v += b2f(resid[(size_t)grow * N + gcol]);
        if (EPI == 3) ((float*)outp)[(size_t)grow * N + gcol] = v;
        else          ((u16*)outp)[(size_t)grow * N + gcol] = f2b(v);
      }
}

// ---------------- V transpose (k-permuted for packed-P PV) -------------------
// VTp[(bh*64+d)*1024 + n0 + p] = V[token n0 + tok(p)][h][d]
// tok(p) = (p>>5)*32 + ((p&31)>>1) + ((p&1)<<4)
__global__ __launch_bounds__(256) void vtrans_k(const u16* __restrict__ QKV,
                                                u16* __restrict__ VT) {
  __shared__ u16 t[64][66];
  const int tid = threadIdx.x;
  const int bh = blockIdx.y;  // s*64 + b*8 + h
  const int sb = bh >> 3, h = bh & 7;
  const int n0 = blockIdx.x * 64;
#pragma unroll
  for (int i = 0; i < 16; i++) {
    int idx = tid + i * 256;
    int r = idx >> 6, c = idx & 63;
    t[r][c] = QKV[((size_t)sb * 1024 + n0 + r) * 1536 + 1024 + h * 64 + c];
  }
  __syncthreads();
#pragma unroll
  for (int i = 0; i < 16; i++) {
    int idx = tid + i * 256;
    int r = idx >> 6, p = idx & 63;  // r=d, p=permuted position
    int tok = ((p >> 5) << 5) + ((p & 31) >> 1) + ((p & 1) << 4);
    VT[((size_t)bh * 64 + r) * 1024 + n0 + p] = t[tok][r];
  }
}

// ---------------- fused self-attention (double-buffered K/V) -----------------
__global__ __launch_bounds__(256) void attn_k(const u16* __restrict__ QKV,
                                              const u16* __restrict__ VT,
                                              u16* __restrict__ Y) {
  // LDS: K(buf) at buf*8192, V(buf) at buf*8192+4096, Pt at 16384 (u16 units)
  __shared__ u16 SM[24576];
  const int STR = 1536;
  const int tid = threadIdx.x, lane = tid & 63, wv = tid >> 6;
  const int lr = lane & 15, lg = lane >> 4;
  const int L = blockIdx.x;       // XCD swizzle: same bh -> same L%8 -> same XCD
  const int by = L & 127;         // s*64 + b*8 + h
  const int q0 = (L >> 7) * 128;
  const int sb = by >> 3, h = by & 7;
  const size_t rowbase = (size_t)sb * 1024;
  const int bcl = (lane & 7) * 16;
  const float SC = 0.18033688f;   // 0.125 * log2(e); P = exp2(score*SC)

  bf16x8 qa[2][2];                // raw Q fragments
#pragma unroll
  for (int m = 0; m < 2; m++)
#pragma unroll
    for (int kk = 0; kk < 2; kk++) {
      int r = q0 + wv * 32 + m * 16 + lr;
      int c = h * 64 + kk * 32 + lg * 8;
      qa[m][kk] = *(const bf16x8*)&QKV[(rowbase + r) * STR + c];
    }

  f32x4 o[2][4];
#pragma unroll
  for (int m = 0; m < 2; m++)
#pragma unroll
    for (int n = 0; n < 4; n++) o[m][n] = f32x4{0.f, 0.f, 0.f, 0.f};
  float ls[2][4] = {{0.f, 0.f, 0.f, 0.f}, {0.f, 0.f, 0.f, 0.f}};

  auto stagekv = [&](int c0, int buf) {
#pragma unroll
    for (int ch = 0; ch < 2; ch++) {
      int r = ch * 32 + (tid >> 3);   // 0..63
      int bcs = bcl ^ ((r & 7) << 4);
      const char* ks =
          (const char*)(QKV + (rowbase + c0 + r) * STR + 512 + h * 64) + bcs;
      gload16(ks, &SM[buf * 8192 + (ch * 32 + wv * 8) * 64]);
      const char* vs =
          (const char*)(VT + ((size_t)by * 64 + r) * 1024 + c0) + bcs;
      gload16(vs, &SM[buf * 8192 + 4096 + (ch * 32 + wv * 8) * 64]);
    }
  };

  stagekv(0, 0);
  __syncthreads();
  for (int t = 0; t < 16; t++) {
    const int buf = t & 1;
    if (t < 15) stagekv((t + 1) * 64, buf ^ 1);   // overlap next-tile loads
    const int Kb = buf * 8192, Vb = buf * 8192 + 4096;

    f32x4 s[2][4];
#pragma unroll
    for (int m = 0; m < 2; m++)
#pragma unroll
      for (int n = 0; n < 4; n++) s[m][n] = f32x4{0.f, 0.f, 0.f, 0.f};
#pragma unroll
    for (int kk = 0; kk < 2; kk++) {
      const int c = kk * 32 + lg * 8;
      bf16x8 kf[4];
#pragma unroll
      for (int n = 0; n < 4; n++) {
        int r = n * 16 + lr;
        kf[n] = *(const bf16x8*)&SM[Kb + r * 64 + (c ^ ((r & 7) << 3))];
      }
#pragma unroll
      for (int m = 0; m < 2; m++)
#pragma unroll
        for (int n = 0; n < 4; n++) s[m][n] = mfma16(qa[m][kk], kf[n], s[m][n]);
    }
    // P = exp2(S*SC); pack col pairs (c, c+16) as u32 at permuted position
#pragma unroll
    for (int m = 0; m < 2; m++)
#pragma unroll
      for (int r = 0; r < 4; r++) {
        int prow = wv * 32 + m * 16 + lg * 4 + r;
        float p00 = __builtin_amdgcn_exp2f(s[m][0][r] * SC);
        float p01 = __builtin_amdgcn_exp2f(s[m][1][r] * SC);
        float p10 = __builtin_amdgcn_exp2f(s[m][2][r] * SC);
        float p11 = __builtin_amdgcn_exp2f(s[m][3][r] * SC);
        ls[m][r] += (p00 + p01) + (p10 + p11);
        bf16x2 w0; w0[0] = (__bf16)p00; w0[1] = (__bf16)p01;
        bf16x2 w1; w1[0] = (__bf16)p10; w1[1] = (__bf16)p11;
        int ib = 16384 + prow * 64, xr = (prow & 7) << 3;
        *(bf16x2*)&SM[ib + ((lr * 2) ^ xr)] = w0;
        *(bf16x2*)&SM[ib + ((32 + lr * 2) ^ xr)] = w1;
      }
    // PV (k-order permuted consistently in Pt and Vt); Pt is wave-private
#pragma unroll
    for (int kc = 0; kc < 2; kc++) {
      const int cc = kc * 32 + lg * 8;
      bf16x8 pa[2], vf[4];
#pragma unroll
      for (int m = 0; m < 2; m++) {
        int r = wv * 32 + m * 16 + lr;
        pa[m] = *(const bf16x8*)&SM[16384 + r * 64 + (cc ^ ((r & 7) << 3))];
      }
#pragma unroll
      for (int n = 0; n < 4; n++) {
        int r = n * 16 + lr;
        vf[n] = *(const bf16x8*)&SM[Vb + r * 64 + (cc ^ ((r & 7) << 3))];
      }
#pragma unroll
      for (int m = 0; m < 2; m++)
#pragma unroll
        for (int n = 0; n < 4; n++) o[m][n] = mfma16(pa[m], vf[n], o[m][n]);
    }
    __syncthreads();
  }

#pragma unroll
  for (int m = 0; m < 2; m++)
#pragma unroll
    for (int r = 0; r < 4; r++) {
      float v = ls[m][r];
      v += __shfl_xor(v, 1); v += __shfl_xor(v, 2);
      v += __shfl_xor(v, 4); v += __shfl_xor(v, 8);
      ls[m][r] = v;
    }
#pragma unroll
  for (int m = 0; m < 2; m++)
#pragma unroll
    for (int n = 0; n < 4; n++)
#pragma unroll
      for (int r = 0; r < 4; r++) {
        int grow = q0 + wv * 32 + m * 16 + lg * 4 + r;
        int gcol = h * 64 + n * 16 + lr;
        Y[(rowbase + grow) * 512 + gcol] = f2b(o[m][n][r] / ls[m][r]);
      }
}

// ---------------- row softmax over 512 (in place, bf16) ----------------------
__global__ __launch_bounds__(256) void rsoftmax_k(u16* __restrict__ X) {
  const int row = blockIdx.x * 4 + (threadIdx.x >> 6);
  const int lane = threadIdx.x & 63;
  u16* p = X + (size_t)row * 512 + lane * 8;
  u16x8 v = *(u16x8*)p;
  float e[8]; float s = 0.f;
#pragma unroll
  for (int j = 0; j < 8; j++) { e[j] = __expf(b2f(v[j])); s += e[j]; }
  for (int x = 1; x < 64; x <<= 1) s += __shfl_xor(s, x);
  float inv = 1.0f / s;
#pragma unroll
  for (int j = 0; j < 8; j++) v[j] = f2b(e[j] * inv);
  *(u16x8*)p = v;
}

// ---------------- 2-key cross attention: one WAVE per token ------------------
// CP[t] (stride 2048): [0:512]=qp [512:1024]=y@kw+bk [1024:1536]=y@vw+bv
//                      [1536:2048]=y_other@vw_s+bv_s
// lane l handles head h=l>>3, chunk (l&7)*8; reduce via shfl within 8 lanes.
__global__ __launch_bounds__(256) void twokey3_k(const u16* __restrict__ CP,
                                                 const u16* __restrict__ KP1,
                                                 const float* __restrict__ cvec,
                                                 u16* __restrict__ o) {
  const int t = blockIdx.x * 4 + (threadIdx.x >> 6);  // token
  const int lane = threadIdx.x & 63;
  const int s = t >> 13;
  const size_t rb = (size_t)t * 2048 + lane * 8;
  u16x8 q8 = *(const u16x8*)&CP[rb];
  u16x8 a8 = *(const u16x8*)&CP[rb + 512];
  u16x8 v0 = *(const u16x8*)&CP[rb + 1024];
  u16x8 v1 = *(const u16x8*)&CP[rb + 1536];
  u16x8 b8 = *(const u16x8*)&KP1[(size_t)t * 512 + lane * 8];
  const float* ck = cvec + s * 512 + lane * 8;
  const float* cv = cvec + 1024 + s * 512 + lane * 8;

  float s0 = 0.f, s1 = 0.f;
#pragma unroll
  for (int j = 0; j < 8; j++) {
    float qf = b2f(q8[j]);
    s0 += qf * (b2f(a8[j]) + ck[j]);
    s1 += qf * b2f(b8[j]);
  }
  // reduce within 8-lane head group
  s0 += __shfl_xor(s0, 1); s1 += __shfl_xor(s1, 1);
  s0 += __shfl_xor(s0, 2); s1 += __shfl_xor(s1, 2);
  s0 += __shfl_xor(s0, 4); s1 += __shfl_xor(s1, 4);

  float e0 = __expf(s0 * 0.125f), e1 = __expf(s1 * 0.125f);
  float rr = 1.0f / (e0 + e1);
  float w0 = e0 * rr, w1 = e1 * rr;
  u16x8 o8;
#pragma unroll
  for (int j = 0; j < 8; j++)
    o8[j] = f2b(w0 * (b2f(v0[j]) + cv[j]) + w1 * b2f(v1[j]));
  *(u16x8*)&o[(size_t)t * 512 + lane * 8] = o8;
}

// =============================================================================
extern "C" void kernel_launch(void* const* d_in, const int* in_sizes, int n_in,
                              void* d_out, int out_size, void* d_ws, size_t ws_size,
                              hipStream_t stream) {
  (void)in_sizes; (void)n_in; (void)out_size; (void)ws_size;
  const float* x0  = (const float*)d_in[0];
  const float* x1  = (const float*)d_in[1];
  const float* Wq  = (const float*)d_in[4];
  const float* Wkv = (const float*)d_in[5];
  const float* Wj1 = (const float*)d_in[6];
  const float* bj1 = (const float*)d_in[7];
  const float* Wj2 = (const float*)d_in[8];
  const float* bj2 = (const float*)d_in[9];
  const float* kn  = (const float*)d_in[10];
  const float* vn  = (const float*)d_in[11];
  const float* Wci[2]  = {(const float*)d_in[12], (const float*)d_in[16]};
  const float* bci[2]  = {(const float*)d_in[13], (const float*)d_in[17]};
  const float* Wco[2]  = {(const float*)d_in[14], (const float*)d_in[18]};
  const float* bco[2]  = {(const float*)d_in[15], (const float*)d_in[19]};
  const float* Wp  = (const float*)d_in[20];
  const float* bp  = (const float*)d_in[21];

  u16* wsb = (u16*)d_ws;
  u16* wqb  = wsb;                       // merged with wkv: 1536x512
  u16* wj1b = wsb + 786432;
  u16* wj2b = wsb + 1310720;
  u16* wcib[2] = {wsb + 1572864, wsb + 2621440};
  u16* wcob[2] = {wsb + 2359296, wsb + 3407872};
  u16* wpb  = wsb + 3670016;
  float* cvecb = (float*)(wsb + 3932160);  // 2048 floats
  const size_t SLOT = 8388608;             // 16 MB in u16
  u16* base = wsb + 4194304;
  u16* S0 = base;                // x bf16 -> REL -> new
  u16* S1 = base + 1 * SLOT;     // y (self-attn out)
  u16* S2 = base + 2 * SLOT;     // QKV (S2..S4) -> HID(S2) -> CP (S2..S5)
  u16* S5 = base + 5 * SLOT;     // VTp -> CP tail
  u16* S6 = base + 6 * SLOT;     // KP1
  u16* S7 = base + 7 * SLOT;     // twokey out
  u16* QKV = S2;
  u16* CP  = S2;
  u16* REL = S0;

  dim3 blk(256), gblk(512);
  xcvt_k<<<dim3(8192), blk, 0, stream>>>(x0, x1, S0);
  wcvt_k<<<dim3(3840), blk, 0, stream>>>(Wq, Wkv, Wj1, Wj2, Wci[0], Wco[0],
                                         Wci[1], Wco[1], Wp, wsb);
  cvec_k<<<dim3(8), blk, 0, stream>>>(kn, vn, wcib[0], wcib[1], cvecb);

  // merged qkv projection: [16384][512] @ [1536][512]^T
  gemm3_k<0, 0, true><<<dim3(128, 12), gblk, 0, stream>>>(
      S0, 512, 512, wqb, wqb, nullptr, nullptr, nullptr, nullptr, QKV, 1536);
  vtrans_k<<<dim3(16, 128), blk, 0, stream>>>(QKV, S5);
  attn_k<<<dim3(1024), blk, 0, stream>>>(QKV, S5, S1);

  // judger
  gemm3_k<1, 3, true><<<dim3(128, 4), gblk, 0, stream>>>(
      S1, 512, 1024, wj1b, wj1b, bj1, bj1, nullptr, nullptr, S2, 512);
  gemm3_k<0, 0, true><<<dim3(128, 4), gblk, 0, stream>>>(
      S2, 512, 512, wj2b, wj2b, bj2, bj2, nullptr, nullptr, REL, 512);
  rsoftmax_k<<<dim3(4096), blk, 0, stream>>>(REL);

  // kp1 = (y*rel) @ kw^T + bk -> S6
  gemm3_k<0, 2, false><<<dim3(128, 4), gblk, 0, stream>>>(
      S1, 512, 512, wcib[0] + 262144, wcib[1] + 262144,
      bci[0] + 512, bci[1] + 512, REL, nullptr, S6, 512);
  // merged cross projection -> CP [16384][2048]  (4th block: y_other @ vw_s)
  gemm3_k<0, 4, true><<<dim3(128, 16), gblk, 0, stream>>>(
      S1, 512, 512, wcib[0], wcib[1], bci[0], bci[1], nullptr, nullptr,
      CP, 2048);

  twokey3_k<<<dim3(4096), blk, 0, stream>>>(CP, S6, cvecb, S7);

  // new = y + o @ Wout^T + bout -> S0 ; out = new @ Wp^T + bp (f32)
  gemm3_k<2, 0, true><<<dim3(128, 4), gblk, 0, stream>>>(
      S7, 512, 512, wcob[0], wcob[1], bco[0], bco[1], nullptr, S1, S0, 512);
  gemm3_k<3, 0, true><<<dim3(128, 4), gblk, 0, stream>>>(
      S0, 512, 512, wpb, wpb, bp, bp, nullptr, nullptr, d_out, 512);
}

// Round 7
// 316.490 us; speedup vs baseline: 2.1235x; 1.0167x over previous
//
#include <hip/hip_runtime.h>

typedef unsigned short u16;
typedef u16 u16x8 __attribute__((ext_vector_type(8)));
typedef __bf16 bf16x8 __attribute__((ext_vector_type(8)));
typedef __bf16 bf16x2 __attribute__((ext_vector_type(2)));
typedef float f32x4 __attribute__((ext_vector_type(4)));

__device__ __forceinline__ float b2f(u16 h) {
  union { unsigned u; float f; } x; x.u = ((unsigned)h) << 16; return x.f;
}
__device__ __forceinline__ u16 f2b(float f) {
  union { float f; unsigned u; } x; x.f = f;
  unsigned r = x.u + 0x7FFFu + ((x.u >> 16) & 1u);
  return (u16)(r >> 16);
}
__device__ __forceinline__ f32x4 mfma16(bf16x8 a, bf16x8 b, f32x4 c) {
  return __builtin_amdgcn_mfma_f32_16x16x32_bf16(a, b, c, 0, 0, 0);
}
__device__ __forceinline__ void gload16(const void* g, void* l) {
  __builtin_amdgcn_global_load_lds(
      (const __attribute__((address_space(1))) void*)g,
      (__attribute__((address_space(3))) void*)l, 16, 0, 0);
}
#define WAITV4 asm volatile("s_waitcnt vmcnt(4)" ::: "memory")
#define WAITV0 asm volatile("s_waitcnt vmcnt(0)" ::: "memory")
#define WAITL0 asm volatile("s_waitcnt lgkmcnt(0)" ::: "memory")
#define BARRIER asm volatile("s_barrier" ::: "memory")

// ---------------- conversions ------------------------------------------------
__global__ __launch_bounds__(256) void xcvt_k(const float* __restrict__ x0,
                                              const float* __restrict__ x1,
                                              u16* __restrict__ out) {
  int b = blockIdx.x;
  const float* src = (b < 4096) ? x0 : x1;
  u16* dst = out + (b < 4096 ? 0 : 4194304);
  int i = (b & 4095) * 1024 + threadIdx.x * 4;
  float4 v = *(const float4*)&src[i];
  dst[i + 0] = f2b(v.x); dst[i + 1] = f2b(v.y);
  dst[i + 2] = f2b(v.z); dst[i + 3] = f2b(v.w);
}

// weight offsets (u16): wq 0, wkv 262144, wj1 786432, wj2 1310720,
// wci0 1572864, wci1 2359296, wp 3145728, wcoT0 3407872, wcoT1 3670016,
// Wfin0 3932160, Wfin1 4456448, cvec(float) @4980736
__global__ __launch_bounds__(256) void wcvt_k(
    const float* __restrict__ wq, const float* __restrict__ wkv,
    const float* __restrict__ wj1, const float* __restrict__ wj2,
    const float* __restrict__ wci0, const float* __restrict__ wci1,
    const float* __restrict__ wp, u16* __restrict__ wsb) {
  int b = blockIdx.x; const float* src; size_t doff; int lb;
  if      (b < 256)  { src = wq;   doff = 0;       lb = b; }
  else if (b < 768)  { src = wkv;  doff = 262144;  lb = b - 256; }
  else if (b < 1280) { src = wj1;  doff = 786432;  lb = b - 768; }
  else if (b < 1536) { src = wj2;  doff = 1310720; lb = b - 1280; }
  else if (b < 2304) { src = wci0; doff = 1572864; lb = b - 1536; }
  else if (b < 3072) { src = wci1; doff = 2359296; lb = b - 2304; }
  else               { src = wp;   doff = 3145728; lb = b - 3072; }
  int i = lb * 1024 + threadIdx.x * 4;
  float4 v = *(const float4*)&src[i];
  u16* dst = wsb + doff + i;
  u16 c0 = f2b(v.x), c1 = f2b(v.y), c2 = f2b(v.z), c3 = f2b(v.w);
  dst[0] = c0; dst[1] = c1; dst[2] = c2; dst[3] = c3;
  if (b >= 3072) {  // Wp also into Wfin0/Wfin1 cols 0-511 (row stride 1024)
    int row = i >> 9, col = i & 511;
    u16* f0 = wsb + 3932160 + (size_t)row * 1024 + col;
    u16* f1 = wsb + 4456448 + (size_t)row * 1024 + col;
    f0[0] = c0; f0[1] = c1; f0[2] = c2; f0[3] = c3;
    f1[0] = c0; f1[1] = c1; f1[2] = c2; f1[3] = c3;
  }
}

// transpose-convert Wco_s (f32 [512][512]) -> bf16 [512][512]^T
__global__ __launch_bounds__(256) void tcvt_k(const float* __restrict__ w0,
                                              const float* __restrict__ w1,
                                              u16* __restrict__ o0,
                                              u16* __restrict__ o1) {
  __shared__ u16 t[64][65];
  const int b = blockIdx.x;           // 128: 64 tiles x 2 mats
  const float* src = (b & 64) ? w1 : w0;
  u16* dst = (b & 64) ? o1 : o0;
  const int r0 = ((b >> 3) & 7) * 64, c0 = (b & 7) * 64;
  const int tid = threadIdx.x;
#pragma unroll
  for (int i = 0; i < 16; i++) {
    int idx = tid + i * 256;
    int r = idx >> 6, c = idx & 63;
    t[r][c] = f2b(src[(size_t)(r0 + r) * 512 + c0 + c]);
  }
  __syncthreads();
#pragma unroll
  for (int i = 0; i < 16; i++) {
    int idx = tid + i * 256;
    int c = idx >> 6, r = idx & 63;
    dst[(size_t)(c0 + c) * 512 + r0 + r] = t[r][c];
  }
}

// cvec[0..1023]=kn_s@kw_s^T, [1024..2047]=vn_s@vw_s^T,
// [2048..3071]=bcomb_s = bp + Wp@bco_s
__global__ __launch_bounds__(256) void cvec_k(
    const float* __restrict__ kn, const float* __restrict__ vn,
    const float* __restrict__ bp, const float* __restrict__ bco0,
    const float* __restrict__ bco1, const u16* __restrict__ wci0,
    const u16* __restrict__ wci1, const u16* __restrict__ wp,
    float* __restrict__ out) {
  int idx = blockIdx.x * 256 + threadIdx.x;  // 3072
  int which = idx >> 9, col = idx & 511;
  const float* src; const u16* w; float acc;
  if (which < 4) {
    int s = which & 1, isv = which >> 1;
    src = (isv ? vn : kn) + s * 512;
    w = (s ? wci1 : wci0) + (isv ? 524288 : 262144) + (size_t)col * 512;
    acc = 0.f;
  } else {
    int s = which & 1;
    src = s ? bco1 : bco0;
    w = wp + (size_t)col * 512;
    acc = bp[col];
  }
  for (int k = 0; k < 512; k += 8) {
    u16x8 w8 = *(const u16x8*)&w[k];
#pragma unroll
    for (int j = 0; j < 8; j++) acc += src[k + j] * b2f(w8[j]);
  }
  out[idx] = acc;
}

// ---------------- GEMM v4: counted-vmcnt dbuf, XCD-chunked grid --------------
// out[M][ostr-matrix, N=ncol*128 cols] = A[M][K]@W[N][K]^T (+epilogue)
// EPI: 0 bf16 out, 1 bf16 gelu(+bias), 3 f32 out
// AMODE: 0 plain, 2 A*mulmat (reg-staged, conservative sync),
//        3 concat(A cols<K1, A[row^8192] cols), 4 cross: col>=1536 -> xor rows
// astr = A row stride; W/bias by output-row block (row0<8192 -> *0)
template<int EPI, int AMODE, bool GLA>
__global__ __launch_bounds__(512, 4) void gemm4_k(
    const u16* __restrict__ A, int astr, int K1, int K,
    const u16* __restrict__ W0, const u16* __restrict__ W1,
    const float* __restrict__ b0, const float* __restrict__ b1,
    const u16* __restrict__ mulmat,
    void* __restrict__ outp, int ostr, int ncol) {
  __shared__ u16 SM[32768];   // A(buf) @ buf*16384, W(buf) @ buf*16384+8192
  const int tid = threadIdx.x;
  const int lane = tid & 63;
  const int wv = tid >> 6;
  const int wr = wv >> 1, wc = wv & 1;
  const int lr = lane & 15, lg = lane >> 4;
  // XCD-chunked block mapping: each XCD owns nrow/8 row panels, cols cycle fast
  const int L = blockIdx.x;
  const int nrow = gridDim.x / ncol;
  int row_b, col_b;
  if ((nrow & 7) == 0) {
    int xcd = L & 7, s = L >> 3;
    row_b = xcd * (nrow >> 3) + s / ncol;
    col_b = s % ncol;
  } else { row_b = L % nrow; col_b = L / nrow; }
  const int row0 = row_b * 128, col0 = col_b * 128;
  const int strm = (row0 >= 8192) ? 1 : 0;
  const u16* W = strm ? W1 : W0;
  const float* bias = strm ? b1 : b0;
  const int shift = (AMODE == 4 && col0 >= 1536) ? 512 : 0;
  const int cxor  = (AMODE == 4 && col0 >= 1536) ? 8192 : 0;
  const int rL = tid >> 3;
  const int bcl = (lane & 7) * 16;

  f32x4 acc[2][4];
#pragma unroll
  for (int m = 0; m < 2; m++)
#pragma unroll
    for (int n = 0; n < 4; n++) acc[m][n] = f32x4{0.f, 0.f, 0.f, 0.f};

  const int nk = K >> 6;

  auto stage = [&](int k0, int buf) {
    const int Ab = buf * 16384, Wb = buf * 16384 + 8192;
#pragma unroll
    for (int ch = 0; ch < 2; ch++) {
      int r = ch * 64 + rL;
      int bcs = bcl ^ ((r & 7) << 4);
      if constexpr (GLA) {
        const char* asrc;
        if constexpr (AMODE == 3) {
          if (k0 < K1)
            asrc = (const char*)(A + (size_t)(row0 + r) * astr) + k0 * 2 + bcs;
          else
            asrc = (const char*)(A + (size_t)((row0 + r) ^ 8192) * astr) +
                   (k0 - K1) * 2 + bcs;
        } else {
          asrc = (const char*)(A + (size_t)((row0 + r) ^ cxor) * astr) +
                 k0 * 2 + bcs;
        }
        gload16(asrc, &SM[Ab + (ch * 64 + wv * 8) * 64]);
      } else {
        int sc = (lane & 7) * 8;
        int kg = k0 + sc;
        u16x8 v = *(const u16x8*)(A + (size_t)(row0 + r) * astr + kg);
        if (AMODE == 2) {
          u16x8 m8 = *(const u16x8*)(mulmat + (size_t)(row0 + r) * K + kg);
#pragma unroll
          for (int j = 0; j < 8; j++) v[j] = f2b(b2f(v[j]) * b2f(m8[j]));
        }
        *(u16x8*)&SM[Ab + r * 64 + (sc ^ ((r & 7) << 3))] = v;
      }
      const char* wsrc =
          (const char*)(W + (size_t)(col0 - shift + r) * K) + k0 * 2 + bcs;
      gload16(wsrc, &SM[Wb + (ch * 64 + wv * 8) * 64]);
    }
  };

  stage(0, 0);
  for (int t = 0; t < nk; t++) {
    const int buf = t & 1;
    if (t + 1 < nk) {
      stage((t + 1) * 64, buf ^ 1);
      if (GLA && AMODE != 2) { WAITV4; } else { WAITV0; }
    } else {
      WAITV0;
    }
    BARRIER;
    const int Ab = buf * 16384, Wb = buf * 16384 + 8192;
#pragma unroll
    for (int kk = 0; kk < 2; kk++) {
      const int c = kk * 32 + lg * 8;
      bf16x8 af[2], wf[4];
#pragma unroll
      for (int m = 0; m < 2; m++) {
        int r = wr * 32 + m * 16 + lr;
        af[m] = *(const bf16x8*)&SM[Ab + r * 64 + (c ^ ((r & 7) << 3))];
      }
#pragma unroll
      for (int n = 0; n < 4; n++) {
        int r = wc * 64 + n * 16 + lr;
        wf[n] = *(const bf16x8*)&SM[Wb + r * 64 + (c ^ ((r & 7) << 3))];
      }
#pragma unroll
      for (int m = 0; m < 2; m++)
#pragma unroll
        for (int n = 0; n < 4; n++)
          acc[m][n] = mfma16(af[m], wf[n], acc[m][n]);
    }
    WAITL0;
    BARRIER;
  }

#pragma unroll
  for (int m = 0; m < 2; m++)
#pragma unroll
    for (int n = 0; n < 4; n++)
#pragma unroll
      for (int r = 0; r < 4; r++) {
        int grow = row0 + wr * 32 + m * 16 + lg * 4 + r;
        int gcol = col0 + wc * 64 + n * 16 + lr;
        float v = acc[m][n][r];
        if (bias) v += bias[gcol - shift];
        if (EPI == 1) v = 0.5f * v * (1.0f + erff(v * 0.70710678118f));
        if (EPI == 3) ((float*)outp)[(size_t)grow * ostr + gcol] = v;
        else          ((u16*)outp)[(size_t)grow * ostr + gcol] = f2b(v);
      }
}

// ---------------- V transpose (k-permuted for packed-P PV) -------------------
__global__ __launch_bounds__(256) void vtrans_k(const u16* __restrict__ QKV,
                                                u16* __restrict__ VT) {
  __shared__ u16 t[64][66];
  const int tid = threadIdx.x;
  const int bh = blockIdx.y;  // s*64 + b*8 + h
  const int sb = bh >> 3, h = bh & 7;
  const int n0 = blockIdx.x * 64;
#pragma unroll
  for (int i = 0; i < 16; i++) {
    int idx = tid + i * 256;
    int r = idx >> 6, c = idx & 63;
    t[r][c] = QKV[((size_t)sb * 1024 + n0 + r) * 1536 + 1024 + h * 64 + c];
  }
  __syncthreads();
#pragma unroll
  for (int i = 0; i < 16; i++) {
    int idx = tid + i * 256;
    int r = idx >> 6, p = idx & 63;
    int tok = ((p >> 5) << 5) + ((p & 31) >> 1) + ((p & 1) << 4);
    VT[((size_t)bh * 64 + r) * 1024 + n0 + p] = t[tok][r];
  }
}

// ---------------- fused self-attention (counted-vmcnt dbuf) ------------------
// writes y into OC[t][0:512] with row stride 1024
__global__ __launch_bounds__(256) void attn_k(const u16* __restrict__ QKV,
                                              const u16* __restrict__ VT,
                                              u16* __restrict__ OC) {
  __shared__ u16 SM[24576];  // K(buf)@buf*8192, V@+4096, Pt@16384
  const int STR = 1536;
  const int tid = threadIdx.x, lane = tid & 63, wv = tid >> 6;
  const int lr = lane & 15, lg = lane >> 4;
  const int L = blockIdx.x;
  const int by = L & 127;
  const int q0 = (L >> 7) * 128;
  const int sb = by >> 3, h = by & 7;
  const size_t rowbase = (size_t)sb * 1024;
  const int bcl = (lane & 7) * 16;
  const float SC = 0.18033688f;

  bf16x8 qa[2][2];
#pragma unroll
  for (int m = 0; m < 2; m++)
#pragma unroll
    for (int kk = 0; kk < 2; kk++) {
      int r = q0 + wv * 32 + m * 16 + lr;
      int c = h * 64 + kk * 32 + lg * 8;
      qa[m][kk] = *(const bf16x8*)&QKV[(rowbase + r) * STR + c];
    }

  f32x4 o[2][4];
#pragma unroll
  for (int m = 0; m < 2; m++)
#pragma unroll
    for (int n = 0; n < 4; n++) o[m][n] = f32x4{0.f, 0.f, 0.f, 0.f};
  float ls[2][4] = {{0.f, 0.f, 0.f, 0.f}, {0.f, 0.f, 0.f, 0.f}};

  auto stagekv = [&](int c0, int buf) {
#pragma unroll
    for (int ch = 0; ch < 2; ch++) {
      int r = ch * 32 + (tid >> 3);
      int bcs = bcl ^ ((r & 7) << 4);
      const char* ks =
          (const char*)(QKV + (rowbase + c0 + r) * STR + 512 + h * 64) + bcs;
      gload16(ks, &SM[buf * 8192 + (ch * 32 + wv * 8) * 64]);
      const char* vs =
          (const char*)(VT + ((size_t)by * 64 + r) * 1024 + c0) + bcs;
      gload16(vs, &SM[buf * 8192 + 4096 + (ch * 32 + wv * 8) * 64]);
    }
  };

  stagekv(0, 0);
  for (int t = 0; t < 16; t++) {
    const int buf = t & 1;
    if (t < 15) {
      stagekv((t + 1) * 64, buf ^ 1);
      WAITV4;
    } else {
      WAITV0;
    }
    BARRIER;
    const int Kb = buf * 8192, Vb = buf * 8192 + 4096;

    f32x4 s[2][4];
#pragma unroll
    for (int m = 0; m < 2; m++)
#pragma unroll
      for (int n = 0; n < 4; n++) s[m][n] = f32x4{0.f, 0.f, 0.f, 0.f};
#pragma unroll
    for (int kk = 0; kk < 2; kk++) {
      const int c = kk * 32 + lg * 8;
      bf16x8 kf[4];
#pragma unroll
      for (int n = 0; n < 4; n++) {
        int r = n * 16 + lr;
        kf[n] = *(const bf16x8*)&SM[Kb + r * 64 + (c ^ ((r & 7) << 3))];
      }
#pragma unroll
      for (int m = 0; m < 2; m++)
#pragma unroll
        for (int n = 0; n < 4; n++) s[m][n] = mfma16(qa[m][kk], kf[n], s[m][n]);
    }
#pragma unroll
    for (int m = 0; m < 2; m++)
#pragma unroll
      for (int r = 0; r < 4; r++) {
        int prow = wv * 32 + m * 16 + lg * 4 + r;
        float p00 = __builtin_amdgcn_exp2f(s[m][0][r] * SC);
        float p01 = __builtin_amdgcn_exp2f(s[m][1][r] * SC);
        float p10 = __builtin_amdgcn_exp2f(s[m][2][r] * SC);
        float p11 = __builtin_amdgcn_exp2f(s[m][3][r] * SC);
        ls[m][r] += (p00 + p01) + (p10 + p11);
        bf16x2 w0; w0[0] = (__bf16)p00; w0[1] = (__bf16)p01;
        bf16x2 w1; w1[0] = (__bf16)p10; w1[1] = (__bf16)p11;
        int ib = 16384 + prow * 64, xr = (prow & 7) << 3;
        *(bf16x2*)&SM[ib + ((lr * 2) ^ xr)] = w0;
        *(bf16x2*)&SM[ib + ((32 + lr * 2) ^ xr)] = w1;
      }
#pragma unroll
    for (int kc = 0; kc < 2; kc++) {
      const int cc = kc * 32 + lg * 8;
      bf16x8 pa[2], vf[4];
#pragma unroll
      for (int m = 0; m < 2; m++) {
        int r = wv * 32 + m * 16 + lr;
        pa[m] = *(const bf16x8*)&SM[16384 + r * 64 + (cc ^ ((r & 7) << 3))];
      }
#pragma unroll
      for (int n = 0; n < 4; n++) {
        int r = n * 16 + lr;
        vf[n] = *(const bf16x8*)&SM[Vb + r * 64 + (cc ^ ((r & 7) << 3))];
      }
#pragma unroll
      for (int m = 0; m < 2; m++)
#pragma unroll
        for (int n = 0; n < 4; n++) o[m][n] = mfma16(pa[m], vf[n], o[m][n]);
    }
    WAITL0;
    BARRIER;
  }

#pragma unroll
  for (int m = 0; m < 2; m++)
#pragma unroll
    for (int r = 0; r < 4; r++) {
      float v = ls[m][r];
      v += __shfl_xor(v, 1); v += __shfl_xor(v, 2);
      v += __shfl_xor(v, 4); v += __shfl_xor(v, 8);
      ls[m][r] = v;
    }
#pragma unroll
  for (int m = 0; m < 2; m++)
#pragma unroll
    for (int n = 0; n < 4; n++)
#pragma unroll
      for (int r = 0; r < 4; r++) {
        int grow = q0 + wv * 32 + m * 16 + lg * 4 + r;
        int gcol = h * 64 + n * 16 + lr;
        OC[(rowbase + grow) * 1024 + gcol] = f2b(o[m][n][r] / ls[m][r]);
      }
}

// ---------------- row softmax over 512 (in place, bf16) ----------------------
__global__ __launch_bounds__(256) void rsoftmax_k(u16* __restrict__ X) {
  const int row = blockIdx.x * 4 + (threadIdx.x >> 6);
  const int lane = threadIdx.x & 63;
  u16* p = X + (size_t)row * 512 + lane * 8;
  u16x8 v = *(u16x8*)p;
  float e[8]; float s = 0.f;
#pragma unroll
  for (int j = 0; j < 8; j++) { e[j] = __expf(b2f(v[j])); s += e[j]; }
  for (int x = 1; x < 64; x <<= 1) s += __shfl_xor(s, x);
  float inv = 1.0f / s;
#pragma unroll
  for (int j = 0; j < 8; j++) v[j] = f2b(e[j] * inv);
  *(u16x8*)p = v;
}

// ---------------- 2-key cross attention: one wave per token ------------------
// writes o into OC[t][512:1024] (row stride 1024)
__global__ __launch_bounds__(256) void twokey3_k(const u16* __restrict__ CP,
                                                 const u16* __restrict__ KP1,
                                                 const float* __restrict__ cvec,
                                                 u16* __restrict__ OC) {
  const int t = blockIdx.x * 4 + (threadIdx.x >> 6);
  const int lane = threadIdx.x & 63;
  const int s = t >> 13;
  const size_t rb = (size_t)t * 2048 + lane * 8;
  u16x8 q8 = *(const u16x8*)&CP[rb];
  u16x8 a8 = *(const u16x8*)&CP[rb + 512];
  u16x8 v0 = *(const u16x8*)&CP[rb + 1024];
  u16x8 v1 = *(const u16x8*)&CP[rb + 1536];
  u16x8 b8 = *(const u16x8*)&KP1[(size_t)t * 512 + lane * 8];
  const float* ck = cvec + s * 512 + lane * 8;
  const float* cv = cvec + 1024 + s * 512 + lane * 8;

  float s0 = 0.f, s1 = 0.f;
#pragma unroll
  for (int j = 0; j < 8; j++) {
    float qf = b2f(q8[j]);
    s0 += qf * (b2f(a8[j]) + ck[j]);
    s1 += qf * b2f(b8[j]);
  }
  s0 += __shfl_xor(s0, 1); s1 += __shfl_xor(s1, 1);
  s0 += __shfl_xor(s0, 2); s1 += __shfl_xor(s1, 2);
  s0 += __shfl_xor(s0, 4); s1 += __shfl_xor(s1, 4);

  float e0 = __expf(s0 * 0.125f), e1 = __expf(s1 * 0.125f);
  float rr = 1.0f / (e0 + e1);
  float w0 = e0 * rr, w1 = e1 * rr;
  u16x8 o8;
#pragma unroll
  for (int j = 0; j < 8; j++)
    o8[j] = f2b(w0 * (b2f(v0[j]) + cv[j]) + w1 * b2f(v1[j]));
  *(u16x8*)&OC[(size_t)t * 1024 + 512 + lane * 8] = o8;
}

// =============================================================================
extern "C" void kernel_launch(void* const* d_in, const int* in_sizes, int n_in,
                              void* d_out, int out_size, void* d_ws, size_t ws_size,
                              hipStream_t stream) {
  (void)in_sizes; (void)n_in; (void)out_size; (void)ws_size;
  const float* x0  = (const float*)d_in[0];
  const float* x1  = (const float*)d_in[1];
  const float* Wq  = (const float*)d_in[4];
  const float* Wkv = (const float*)d_in[5];
  const float* Wj1 = (const float*)d_in[6];
  const float* bj1 = (const float*)d_in[7];
  const float* Wj2 = (const float*)d_in[8];
  const float* bj2 = (const float*)d_in[9];
  const float* kn  = (const float*)d_in[10];
  const float* vn  = (const float*)d_in[11];
  const float* Wci[2]  = {(const float*)d_in[12], (const float*)d_in[16]};
  const float* bci[2]  = {(const float*)d_in[13], (const float*)d_in[17]};
  const float* Wco[2]  = {(const float*)d_in[14], (const float*)d_in[18]};
  const float* bco[2]  = {(const float*)d_in[15], (const float*)d_in[19]};
  const float* Wp  = (const float*)d_in[20];
  const float* bp  = (const float*)d_in[21];

  u16* wsb = (u16*)d_ws;
  u16* wqb   = wsb;                 // merged [1536][512]
  u16* wj1b  = wsb + 786432;
  u16* wj2b  = wsb + 1310720;
  u16* wcib[2] = {wsb + 1572864, wsb + 2359296};
  u16* wpb   = wsb + 3145728;
  u16* wcoT[2] = {wsb + 3407872, wsb + 3670016};
  u16* wfin[2] = {wsb + 3932160, wsb + 4456448};  // [512][1024]
  float* cvecb = (float*)(wsb + 4980736);          // 3072 floats
  const size_t SLOT = 8388608;                     // 16 MB in u16
  u16* base = wsb + 5242880;                       // 10 MB offset
  u16* S0 = base;                // x -> HID -> KP1
  u16* OC = base + 1 * SLOT;     // [16384][1024]: y | o  (S1..S2)
  u16* S3 = base + 3 * SLOT;     // QKV(S3..S5) -> REL -> CP(S3..S6)
  u16* S4 = base + 4 * SLOT;
  u16* S5 = base + 5 * SLOT;
  u16* S6 = base + 6 * SLOT;     // VT
  u16* QKV = S3;
  u16* REL = S3;
  u16* CP  = S3;
  (void)S4; (void)S5;

  dim3 blk(256), gblk(512);
  xcvt_k<<<dim3(8192), blk, 0, stream>>>(x0, x1, S0);
  wcvt_k<<<dim3(3328), blk, 0, stream>>>(Wq, Wkv, Wj1, Wj2, Wci[0], Wci[1],
                                         Wp, wsb);
  tcvt_k<<<dim3(128), blk, 0, stream>>>(Wco[0], Wco[1], wcoT[0], wcoT[1]);
  cvec_k<<<dim3(12), blk, 0, stream>>>(kn, vn, bp, bco[0], bco[1],
                                       wcib[0], wcib[1], wpb, cvecb);
  // Wcomb_s = Wp @ Wco_s -> Wfin_s cols 512-1023
  for (int s = 0; s < 2; s++)
    gemm4_k<0, 0, true><<<dim3(16), gblk, 0, stream>>>(
        wpb, 512, 512, 512, wcoT[s], wcoT[s], nullptr, nullptr, nullptr,
        wfin[s] + 512, 1024, 4);

  // qkv projection: [16384][512] @ [1536][512]^T -> QKV
  gemm4_k<0, 0, true><<<dim3(1536), gblk, 0, stream>>>(
      S0, 512, 512, 512, wqb, wqb, nullptr, nullptr, nullptr, QKV, 1536, 12);
  vtrans_k<<<dim3(16, 128), blk, 0, stream>>>(QKV, S6);
  attn_k<<<dim3(1024), blk, 0, stream>>>(QKV, S6, OC);   // y -> OC[:,0:512]

  // judger
  gemm4_k<1, 3, true><<<dim3(512), gblk, 0, stream>>>(
      OC, 1024, 512, 1024, wj1b, wj1b, bj1, bj1, nullptr, S0, 512, 4);
  gemm4_k<0, 0, true><<<dim3(512), gblk, 0, stream>>>(
      S0, 512, 512, 512, wj2b, wj2b, bj2, bj2, nullptr, REL, 512, 4);
  rsoftmax_k<<<dim3(4096), blk, 0, stream>>>(REL);

  // kp1 = (y*rel) @ kw^T + bk -> S0
  gemm4_k<0, 2, false><<<dim3(512), gblk, 0, stream>>>(
      OC, 1024, 512, 512, wcib[0] + 262144, wcib[1] + 262144,
      bci[0] + 512, bci[1] + 512, REL, S0, 512, 4);
  // merged cross projection -> CP [16384][2048] (4th block: y_other @ vw_s)
  gemm4_k<0, 4, true><<<dim3(2048), gblk, 0, stream>>>(
      OC, 1024, 512, 512, wcib[0], wcib[1], bci[0], bci[1], nullptr,
      CP, 2048, 16);

  twokey3_k<<<dim3(4096), blk, 0, stream>>>(CP, S0, cvecb, OC);

  // out = [y|o] @ [Wp | Wp@Wco_s]^T + bcomb_s  (f32)
  gemm4_k<3, 0, true><<<dim3(512), gblk, 0, stream>>>(
      OC, 1024, 1024, 1024, wfin[0], wfin[1], cvecb + 2048, cvecb + 2560,
      nullptr, d_out, 512, 4);
}